// Round 5
// baseline (2973.206 us; speedup 1.0000x reference)
//
#include <hip/hip_runtime.h>
#include <math.h>

// GNN_node_Virtualnode: B=128 graphs, 256 nodes/graph, 2048 edges/graph,
// emb=256, 5 GIN layers + virtual node, learned dense-adjacency propagation.
// Round 5: bgemm 3 blocks/CU (B-lo direct from global, 48KB LDS);
// vn colsum fused into k_agg via atomics (k_vn is MLP-only);
// XCD-swizzled k_agg for per-graph L2 locality.

#define B_G   128
#define NPG   256
#define EPG   2048
#define EMB   256
#define NL    5
#define NNODE (B_G*NPG)   // 32768
#define NEDGE (B_G*EPG)   // 262144
#define FBUF  8388608     // floats per 33.55MB buffer

typedef __attribute__((ext_vector_type(8))) short bf16x8;
typedef __attribute__((ext_vector_type(4))) float f32x4;

// ---------------- helpers ----------------
__device__ __forceinline__ void split1(float x, unsigned short& h, unsigned short& l) {
  // round-to-nearest-even bf16 hi, then bf16(residual)
  unsigned u = __builtin_bit_cast(unsigned, x);
  unsigned hr = u + 0x7FFFu + ((u >> 16) & 1u);
  h = (unsigned short)(hr >> 16);
  float hf = __builtin_bit_cast(float, hr & 0xFFFF0000u);
  float r = x - hf;
  unsigned v = __builtin_bit_cast(unsigned, r);
  unsigned lr = v + 0x7FFFu + ((v >> 16) & 1u);
  l = (unsigned short)(lr >> 16);
}

__device__ __forceinline__ float bdec(unsigned short h) {
  return __builtin_bit_cast(float, (unsigned)h << 16);
}

__device__ __forceinline__ void gload16(unsigned short* lds, const unsigned short* g) {
  // async global->LDS, 16B/lane; LDS dest = wave-uniform base + lane*16
  __builtin_amdgcn_global_load_lds(
      (const __attribute__((address_space(1))) unsigned int*)g,
      (__attribute__((address_space(3))) unsigned int*)lds, 16, 0, 0);
}

__global__ void k_zero(uint4* p, int n16) {
  int i = blockIdx.x * 256 + threadIdx.x;
  if (i < n16) p[i] = make_uint4(0, 0, 0, 0);
}

// 16-entry sigmoid edge-weight table: 16 waves, one per bond value
__global__ void k_ewtbl(const float* __restrict__ bh, const float* __restrict__ w,
                        const float* __restrict__ b, float* __restrict__ tbl) {
  int v = threadIdx.x >> 6, t = threadIdx.x & 63;
  float p = bh[v * 64 + t] * w[t];
  for (int off = 32; off; off >>= 1) p += __shfl_down(p, off, 64);
  if (t == 0) tbl[v] = 1.0f / (1.0f + expf(-(p + b[0])));
}

// Deterministic duplicate resolution: last edge (max e) wins.
__global__ void k_pack_adj(const int* __restrict__ lei, const int* __restrict__ ea,
                           int* __restrict__ packed) {
  int idx = blockIdx.x * 256 + threadIdx.x;       // NEDGE
  int g = idx >> 11, e = idx & 2047;
  int s = lei[g * 4096 + e];
  int d = lei[g * 4096 + 2048 + e];
  int v = ((e + 1) << 4) | ea[g * 2048 + e];
  atomicMax(&packed[g * 65536 + s * 256 + d], v);
}

__global__ void k_unpack_adj(const int* __restrict__ packed,
                             const float* __restrict__ tbl, float* __restrict__ adj) {
  int idx = blockIdx.x * 256 + threadIdx.x;       // 8388608
  int v = packed[idx];
  adj[idx] = v ? tbl[v & 15] : 0.0f;
}

__global__ void k_addeye(float* __restrict__ adj) {
  int idx = blockIdx.x * 256 + threadIdx.x;       // NNODE
  int g = idx >> 8, i = idx & 255;
  adj[g * 65536 + i * 257] += 1.0f;
}

// A[i][j] = colsum(i)^-1/2 * adj[i][j] * rowsum(j)^-1/2  (in place)
__global__ __launch_bounds__(256)
void k_degnorm(float* __restrict__ adj) {
  int g = blockIdx.x, t = threadIdx.x;
  float* Ag = adj + (size_t)g * 65536;
  __shared__ float cs[256];
  float s0 = 0, s1 = 0, s2 = 0, s3 = 0;
  for (int i = 0; i < 256; i += 4) {
    s0 += Ag[(i + 0) * 256 + t]; s1 += Ag[(i + 1) * 256 + t];
    s2 += Ag[(i + 2) * 256 + t]; s3 += Ag[(i + 3) * 256 + t];
  }
  cs[t] = rsqrtf((s0 + s1) + (s2 + s3));          // colsum(t)^-1/2
  float4 r0 = make_float4(0, 0, 0, 0), r1 = r0, r2 = r0, r3 = r0;
  const float4* A4 = (const float4*)(Ag + t * 256);
  for (int j = 0; j < 64; j += 4) {
    float4 v0 = A4[j], v1 = A4[j + 1], v2 = A4[j + 2], v3 = A4[j + 3];
    r0.x += v0.x + v0.y; r0.y += v0.z + v0.w;
    r1.x += v1.x + v1.y; r1.y += v1.z + v1.w;
    r2.x += v2.x + v2.y; r2.y += v2.z + v2.w;
    r3.x += v3.x + v3.y; r3.y += v3.z + v3.w;
  }
  float rc = rsqrtf((r0.x + r0.y) + (r1.x + r1.y) + (r2.x + r2.y) + (r3.x + r3.y));
  __syncthreads();
  for (int i = 0; i < 256; i++) Ag[i * 256 + t] = cs[i] * Ag[i * 256 + t] * rc;
}

// transposed fea gather: X0t[g][e][n] = Yt[g][e][n] = atom_emb[aidx[g*256+n]][e]
__global__ void k_feaT(const int* __restrict__ aidx, const float* __restrict__ aemb,
                       float* __restrict__ X0t, float* __restrict__ Yt) {
  int i = blockIdx.x * 256 + threadIdx.x;          // 8388608
  int g = i >> 16, e = (i >> 8) & 255, n = i & 255;
  int av = aidx[g * 256 + n];
  float v = aemb[av * 256 + e];
  X0t[i] = v; Yt[i] = v;
}

// generic LDS-tiled transpose: dst[z][N][K] = scale * src[z][K][N]
__global__ __launch_bounds__(256)
void k_transp(const float* __restrict__ src, float* __restrict__ dst,
              int K, int N, long ss, long sd, float scale) {
  __shared__ float tl[64][65];
  src += (size_t)blockIdx.z * ss; dst += (size_t)blockIdx.z * sd;
  int n0 = blockIdx.x * 64, k0 = blockIdx.y * 64;
  int t = threadIdx.x;
  int c = (t & 15) * 4, r = t >> 4;
#pragma unroll
  for (int p = 0; p < 4; p++) {
    int rr = r + p * 16;
    float4 v = *(const float4*)&src[(size_t)(k0 + rr) * N + n0 + c];
    tl[rr][c] = v.x; tl[rr][c + 1] = v.y; tl[rr][c + 2] = v.z; tl[rr][c + 3] = v.w;
  }
  __syncthreads();
#pragma unroll
  for (int p = 0; p < 4; p++) {
    int rr = r + p * 16;
    float4 o;
    o.x = tl[c][rr] * scale;     o.y = tl[c + 1][rr] * scale;
    o.z = tl[c + 2][rr] * scale; o.w = tl[c + 3][rr] * scale;
    *(float4*)&dst[(size_t)(n0 + rr) * K + k0 + c] = o;
  }
}

// fused transpose + hi/lo split: dh/dl[z][N][K] = split(src[z][K][N])
__global__ __launch_bounds__(256)
void k_wtsplit(const float* __restrict__ src, unsigned short* __restrict__ dh,
               unsigned short* __restrict__ dl, int K, int N, long ss, long sd) {
  __shared__ float tl[64][65];
  src += (size_t)blockIdx.z * ss;
  dh += (size_t)blockIdx.z * sd; dl += (size_t)blockIdx.z * sd;
  int n0 = blockIdx.x * 64, k0 = blockIdx.y * 64;
  int t = threadIdx.x;
  int c = (t & 15) * 4, r = t >> 4;
#pragma unroll
  for (int p = 0; p < 4; p++) {
    int rr = r + p * 16;
    float4 v = *(const float4*)&src[(size_t)(k0 + rr) * N + n0 + c];
    tl[rr][c] = v.x; tl[rr][c + 1] = v.y; tl[rr][c + 2] = v.z; tl[rr][c + 3] = v.w;
  }
  __syncthreads();
#pragma unroll
  for (int p = 0; p < 4; p++) {
    int rr = r + p * 16;
    ushort4 hh, ll;
    split1(tl[c][rr],     hh.x, ll.x);
    split1(tl[c + 1][rr], hh.y, ll.y);
    split1(tl[c + 2][rr], hh.z, ll.z);
    split1(tl[c + 3][rr], hh.w, ll.w);
    size_t o = (size_t)(n0 + rr) * K + k0 + c;
    *(ushort4*)&dh[o] = hh; *(ushort4*)&dl[o] = ll;
  }
}

// ---- prop GEMM (fp32 inputs, in-kernel split; validated R2 kernel) ----
// C[z][M][N] = A[z][M][K] @ Bt[z][N][K]^T ; optional Yacc += C.
__global__ __launch_bounds__(256, 2)
void k_mgemm(const float* __restrict__ A, const float* __restrict__ Bt,
             float* __restrict__ C, float* __restrict__ Yacc, int K, int N,
             long sA, long sBt, long sC) {
  __shared__ alignas(16) unsigned short Ah[128 * 64], Al[128 * 64];
  __shared__ alignas(16) unsigned short Bh[128 * 64], Bl[128 * 64];
  int z = blockIdx.z;
  A += (size_t)z * sA; Bt += (size_t)z * sBt; C += (size_t)z * sC;
  float* Yp = Yacc ? Yacc + (size_t)z * sC : nullptr;
  int rowbase = blockIdx.y * 128, colbase = blockIdx.x * 128;
  int t = threadIdx.x, l = t & 63, w = t >> 6;
  int wr = w >> 1, wc = w & 1;
  f32x4 acc[4][4];
#pragma unroll
  for (int i = 0; i < 4; i++)
#pragma unroll
    for (int j = 0; j < 4; j++) acc[i][j] = (f32x4){0, 0, 0, 0};

  for (int k0 = 0; k0 < K; k0 += 64) {
    __syncthreads();
    for (int p = 0; p < 8; p++) {
      int flat = p * 256 + t;                    // 0..2047
      int r = flat >> 4, kq = (flat & 15) * 4;   // row 0..127, k-quad
      float4 va = *(const float4*)&A[(size_t)(rowbase + r) * K + k0 + kq];
      int off = ((r * 128 + kq * 2) ^ ((r & 7) << 4)) >> 1;  // short index
      ushort4 hh, ll;
      split1(va.x, hh.x, ll.x); split1(va.y, hh.y, ll.y);
      split1(va.z, hh.z, ll.z); split1(va.w, hh.w, ll.w);
      *(ushort4*)&Ah[off] = hh; *(ushort4*)&Al[off] = ll;
      float4 vb = *(const float4*)&Bt[(size_t)(colbase + r) * K + k0 + kq];
      split1(vb.x, hh.x, ll.x); split1(vb.y, hh.y, ll.y);
      split1(vb.z, hh.z, ll.z); split1(vb.w, hh.w, ll.w);
      *(ushort4*)&Bh[off] = hh; *(ushort4*)&Bl[off] = ll;
    }
    __syncthreads();
#pragma unroll
    for (int ks = 0; ks < 2; ks++) {
      bf16x8 ah[4], al_[4], bh[4], bl[4];
#pragma unroll
      for (int fm = 0; fm < 4; fm++) {
        int r = wr * 64 + fm * 16 + (l & 15);
        int off = (r * 64 + ks * 32 + (l >> 4) * 8) ^ ((r & 7) << 3);
        ah[fm] = *(const bf16x8*)&Ah[off];
        al_[fm] = *(const bf16x8*)&Al[off];
      }
#pragma unroll
      for (int fn = 0; fn < 4; fn++) {
        int c = wc * 64 + fn * 16 + (l & 15);
        int off = (c * 64 + ks * 32 + (l >> 4) * 8) ^ ((c & 7) << 3);
        bh[fn] = *(const bf16x8*)&Bh[off];
        bl[fn] = *(const bf16x8*)&Bl[off];
      }
#pragma unroll
      for (int fm = 0; fm < 4; fm++)
#pragma unroll
        for (int fn = 0; fn < 4; fn++) {
          acc[fm][fn] = __builtin_amdgcn_mfma_f32_16x16x32_bf16(ah[fm], bh[fn], acc[fm][fn], 0, 0, 0);
          acc[fm][fn] = __builtin_amdgcn_mfma_f32_16x16x32_bf16(ah[fm], bl[fn], acc[fm][fn], 0, 0, 0);
          acc[fm][fn] = __builtin_amdgcn_mfma_f32_16x16x32_bf16(al_[fm], bh[fn], acc[fm][fn], 0, 0, 0);
        }
    }
  }
#pragma unroll
  for (int fm = 0; fm < 4; fm++)
#pragma unroll
    for (int r4 = 0; r4 < 4; r4++) {
      int row = rowbase + wr * 64 + fm * 16 + (l >> 4) * 4 + r4;
#pragma unroll
      for (int fn = 0; fn < 4; fn++) {
        int col = colbase + wc * 64 + fn * 16 + (l & 15);
        float v = acc[fm][fn][r4];
        size_t idx = (size_t)row * N + col;
        if (Yp) Yp[idx] += v;
        C[idx] = v;
      }
    }
}

// ---- MLP GEMM: pre-split bf16 hi/lo, global_load_lds staging (Ah/Al/Bh);
// B-lo fragments loaded direct global->VGPR (weights L2-resident).
// 48KB LDS -> 3 blocks/CU. Fused column sum/sumsq. Output fp32 or bf16 pair.
__global__ __launch_bounds__(256, 3)
void k_bgemm(const unsigned short* __restrict__ Ah_g, const unsigned short* __restrict__ Al_g,
             const unsigned short* __restrict__ Bh_g, const unsigned short* __restrict__ Bl_g,
             const float* __restrict__ bias, float* __restrict__ Cf,
             unsigned short* __restrict__ Ch, unsigned short* __restrict__ Cl,
             float* __restrict__ Ssum, float* __restrict__ Ssq, int K, int N) {
  __shared__ alignas(16) unsigned short Ah[128 * 64], Al[128 * 64];
  __shared__ alignas(16) unsigned short Bh[128 * 64];
  int rowbase = blockIdx.y * 128, colbase = blockIdx.x * 128;
  int t = threadIdx.x, l = t & 63, wid = t >> 6;
  int wr = wid >> 1, wc = wid & 1;
  int r8 = l >> 3, cb = (l & 7) * 8;               // staging lane -> (row, col)
  f32x4 acc[4][4];
#pragma unroll
  for (int i = 0; i < 4; i++)
#pragma unroll
    for (int j = 0; j < 4; j++) acc[i][j] = (f32x4){0, 0, 0, 0};

  for (int k0 = 0; k0 < K; k0 += 64) {
    __syncthreads();                               // prior readers done
#pragma unroll
    for (int i = 0; i < 4; i++) {
      int chunk = wid * 4 + i;                     // 0..15 -> 8 rows each
      int row = chunk * 8 + r8;
      size_t goA = (size_t)(rowbase + row) * K + k0 + cb;
      size_t goB = (size_t)(colbase + row) * K + k0 + cb;
      gload16(Ah + chunk * 512, Ah_g + goA);
      gload16(Al + chunk * 512, Al_g + goA);
      gload16(Bh + chunk * 512, Bh_g + goB);
    }
    bf16x8 blr[2][4];                              // B-lo direct from global
#pragma unroll
    for (int ks = 0; ks < 2; ks++)
#pragma unroll
      for (int fn = 0; fn < 4; fn++) {
        int c = colbase + wc * 64 + fn * 16 + (l & 15);
        blr[ks][fn] = *(const bf16x8*)&Bl_g[(size_t)c * K + k0 + ks * 32 + (l >> 4) * 8];
      }
    __syncthreads();                               // vmcnt(0) drain + barrier
#pragma unroll
    for (int ks = 0; ks < 2; ks++) {
      bf16x8 ah[4], al_[4], bh[4];
#pragma unroll
      for (int fm = 0; fm < 4; fm++) {
        int r = wr * 64 + fm * 16 + (l & 15);
        ah[fm]  = *(const bf16x8*)&Ah[r * 64 + ks * 32 + (l >> 4) * 8];
        al_[fm] = *(const bf16x8*)&Al[r * 64 + ks * 32 + (l >> 4) * 8];
      }
#pragma unroll
      for (int fn = 0; fn < 4; fn++) {
        int c = wc * 64 + fn * 16 + (l & 15);
        bh[fn] = *(const bf16x8*)&Bh[c * 64 + ks * 32 + (l >> 4) * 8];
      }
#pragma unroll
      for (int fm = 0; fm < 4; fm++)
#pragma unroll
        for (int fn = 0; fn < 4; fn++) {
          acc[fm][fn] = __builtin_amdgcn_mfma_f32_16x16x32_bf16(ah[fm], bh[fn], acc[fm][fn], 0, 0, 0);
          acc[fm][fn] = __builtin_amdgcn_mfma_f32_16x16x32_bf16(ah[fm], blr[ks][fn], acc[fm][fn], 0, 0, 0);
          acc[fm][fn] = __builtin_amdgcn_mfma_f32_16x16x32_bf16(al_[fm], bh[fn], acc[fm][fn], 0, 0, 0);
        }
    }
  }
  __syncthreads();
  float bi[4], scoll[4] = {0, 0, 0, 0}, qcoll[4] = {0, 0, 0, 0};
#pragma unroll
  for (int fn = 0; fn < 4; fn++)
    bi[fn] = bias ? bias[colbase + wc * 64 + fn * 16 + (l & 15)] : 0.0f;
#pragma unroll
  for (int fm = 0; fm < 4; fm++)
#pragma unroll
    for (int r4 = 0; r4 < 4; r4++) {
      int row = rowbase + wr * 64 + fm * 16 + (l >> 4) * 4 + r4;
#pragma unroll
      for (int fn = 0; fn < 4; fn++) {
        int col = colbase + wc * 64 + fn * 16 + (l & 15);
        float v = acc[fm][fn][r4] + bi[fn];
        size_t idx = (size_t)row * N + col;
        if (Cf) Cf[idx] = v;
        if (Ch) { unsigned short hh, ll; split1(v, hh, ll); Ch[idx] = hh; Cl[idx] = ll; }
        scoll[fn] += v; qcoll[fn] += v * v;
      }
    }
  if (Ssum) {
    float* scr = (float*)Ah;                       // 256 floats scratch
    scr[t] = 0.0f;
    __syncthreads();
#pragma unroll
    for (int fn = 0; fn < 4; fn++) {
      int cl_ = wc * 64 + fn * 16 + (l & 15);
      atomicAdd(&scr[cl_ * 2], scoll[fn]);
      atomicAdd(&scr[cl_ * 2 + 1], qcoll[fn]);
    }
    __syncthreads();
    if (t < 128) {
      atomicAdd(&Ssum[colbase + t], scr[t * 2]);
      atomicAdd(&Ssq[colbase + t], scr[t * 2 + 1]);
    }
  }
}

// in-place BN(+relu) on T1 hi/lo pairs; BN1 finalize fused (reads raw stats)
__global__ void k_bnsplit(unsigned short* __restrict__ Th, unsigned short* __restrict__ Tl,
                          const float* __restrict__ Ssum, const float* __restrict__ Ssq,
                          const float* __restrict__ g, const float* __restrict__ b) {
  size_t i = (size_t)blockIdx.x * 256 + threadIdx.x;  // 4.19M threads x4 elems
  int c4 = ((int)i & 127) * 4;
  ushort4 h4 = *(ushort4*)&Th[i * 4];
  ushort4 l4 = *(ushort4*)&Tl[i * 4];
  float4 ss = *(const float4*)&Ssum[c4], qq = *(const float4*)&Ssq[c4];
  float4 gg = *(const float4*)&g[c4],    bb = *(const float4*)&b[c4];
  const float invN = 1.0f / 32768.0f;
  float x, mu, var, sc, sh;
#define BNS(cmp) \
  mu = ss.cmp * invN; var = qq.cmp * invN - mu * mu; \
  sc = rsqrtf(var + 1e-5f) * gg.cmp; sh = bb.cmp - mu * sc; \
  x = bdec(h4.cmp) + bdec(l4.cmp); x = fmaf(x, sc, sh); x = x > 0 ? x : 0; \
  split1(x, h4.cmp, l4.cmp);
  BNS(x) BNS(y) BNS(z) BNS(w)
#undef BNS
  *(ushort4*)&Th[i * 4] = h4;
  *(ushort4*)&Tl[i * 4] = l4;
}

// ---- CSR build (edge structure is layer-invariant; built once) ----
__global__ void k_count(const int* __restrict__ lei, int* __restrict__ counts) {
  int idx = blockIdx.x * 256 + threadIdx.x;
  int g = idx >> 11, e = idx & 2047;
  int d = lei[g * 4096 + 2048 + e];
  atomicAdd(&counts[g * 256 + d], 1);
}

__global__ void k_scan(const int* __restrict__ counts, int* __restrict__ rowptr,
                       int* __restrict__ pos) {
  int g = blockIdx.x, t = threadIdx.x;
  __shared__ int sc[256];
  int own = counts[g * 256 + t];
  sc[t] = own;
  __syncthreads();
  for (int off = 1; off < 256; off <<= 1) {
    int v = 0;
    if (t >= off) v = sc[t - off];
    __syncthreads();
    sc[t] += v;
    __syncthreads();
  }
  int val = g * 2048 + sc[t] - own; // exclusive
  rowptr[g * 256 + t] = val;
  pos[g * 256 + t] = val;
  if (g == B_G - 1 && t == 255) rowptr[B_G * 256] = B_G * 2048;
}

__global__ void k_fill(const int* __restrict__ lei, const int* __restrict__ ea,
                       int* __restrict__ pos, int* __restrict__ csr) {
  int idx = blockIdx.x * 256 + threadIdx.x;
  int g = idx >> 11, e = idx & 2047;
  int s = lei[g * 4096 + e];
  int d = lei[g * 4096 + 2048 + e];
  int eav = ea[g * 2048 + e];
  int slot = atomicAdd(&pos[g * 256 + d], 1);
  csr[slot] = s | (eav << 16);
}

// z = (1+eps)*(h+vn) + sum_{e->this} relu(h[src]+vn+eemb[ea]); out bf16 pair.
// Also accumulates per-graph column sums of transformed h into VNT (atomics).
// XCD-swizzled: 64 blocks of one graph land on one XCD (L2-resident gathers).
__global__ __launch_bounds__(256)
void k_agg(const float* __restrict__ H,
           const float* __restrict__ hsc, const float* __restrict__ hsh,
           const float* __restrict__ vn, int vns,
           const float* __restrict__ eemb,
           const int* __restrict__ rowptr, const int* __restrict__ csr,
           const float* __restrict__ geps, int l,
           unsigned short* __restrict__ Zh, unsigned short* __restrict__ Zl,
           float* __restrict__ VNT) {
  __shared__ float ee[16 * 256];
  for (int i = threadIdx.x; i < 4096; i += 256) ee[i] = eemb[i];
  __syncthreads();
  int lane = threadIdx.x & 63, w = threadIdx.x >> 6;
  int bid = (blockIdx.x & 7) * 1024 + (blockIdx.x >> 3);  // XCD swizzle (8192=8*1024)
  int m = bid * 4 + w;
  int g = m >> 8;
  int d = lane * 4;
  float eps1 = 1.0f + geps[l];
  float4 sc4 = make_float4(0, 0, 0, 0), sh4 = make_float4(0, 0, 0, 0);
  if (hsc) { sc4 = *(const float4*)&hsc[d]; sh4 = *(const float4*)&hsh[d]; }
  float4 vn4 = *(const float4*)&vn[(size_t)g * vns + d];
  int rp = rowptr[m], rp1 = rowptr[m + 1];
  float4 acc = make_float4(0, 0, 0, 0);
  int gbase = g << 8;
  for (int j = rp; j < rp1; j++) {
    int cw = csr[j];
    int src = cw & 0xFFFF, eav = cw >> 16;
    float4 h4 = *(const float4*)&H[(size_t)(gbase + src) * 256 + d];
    if (hsc) {
      h4.x = fmaf(h4.x, sc4.x, sh4.x); h4.y = fmaf(h4.y, sc4.y, sh4.y);
      h4.z = fmaf(h4.z, sc4.z, sh4.z); h4.w = fmaf(h4.w, sc4.w, sh4.w);
      h4.x = h4.x > 0 ? h4.x : 0; h4.y = h4.y > 0 ? h4.y : 0;
      h4.z = h4.z > 0 ? h4.z : 0; h4.w = h4.w > 0 ? h4.w : 0;
    }
    const float4 e4 = *(const float4*)&ee[eav * 256 + d];
    float mx = h4.x + vn4.x + e4.x; float my = h4.y + vn4.y + e4.y;
    float mz = h4.z + vn4.z + e4.z; float mw = h4.w + vn4.w + e4.w;
    acc.x += mx > 0 ? mx : 0; acc.y += my > 0 ? my : 0;
    acc.z += mz > 0 ? mz : 0; acc.w += mw > 0 ? mw : 0;
  }
  float4 hs = *(const float4*)&H[(size_t)m * 256 + d];
  if (hsc) {
    hs.x = fmaf(hs.x, sc4.x, sh4.x); hs.y = fmaf(hs.y, sc4.y, sh4.y);
    hs.z = fmaf(hs.z, sc4.z, sh4.z); hs.w = fmaf(hs.w, sc4.w, sh4.w);
    hs.x = hs.x > 0 ? hs.x : 0; hs.y = hs.y > 0 ? hs.y : 0;
    hs.z = hs.z > 0 ? hs.z : 0; hs.w = hs.w > 0 ? hs.w : 0;
  }
  // per-graph column sums of transformed h (feeds vn MLP); avoids k_vn H re-read
  atomicAdd(&VNT[g * 256 + d + 0], hs.x);
  atomicAdd(&VNT[g * 256 + d + 1], hs.y);
  atomicAdd(&VNT[g * 256 + d + 2], hs.z);
  atomicAdd(&VNT[g * 256 + d + 3], hs.w);
  float4 z4;
  z4.x = eps1 * (hs.x + vn4.x) + acc.x;
  z4.y = eps1 * (hs.y + vn4.y) + acc.y;
  z4.z = eps1 * (hs.z + vn4.z) + acc.z;
  z4.w = eps1 * (hs.w + vn4.w) + acc.w;
  ushort4 hh, ll;
  split1(z4.x, hh.x, ll.x); split1(z4.y, hh.y, ll.y);
  split1(z4.z, hh.z, ll.z); split1(z4.w, hh.w, ll.w);
  *(ushort4*)&Zh[(size_t)m * 256 + d] = hh;
  *(ushort4*)&Zl[(size_t)m * 256 + d] = ll;
}

// vn_out = relu(relu(vt@W1+B1)@W2+B2), vt = VNT[g] + 257*vn
__global__ __launch_bounds__(256)
void k_vn(const float* __restrict__ VNT,
          const float* __restrict__ vn_in, int vns,
          const float* __restrict__ W1, const float* __restrict__ B1,
          const float* __restrict__ W2, const float* __restrict__ B2,
          float* __restrict__ vn_out) {
  int g = blockIdx.x, t = threadIdx.x;
  __shared__ float vt[256];
  __shared__ float u[512];
  vt[t] = VNT[g * 256 + t] + 257.0f * vn_in[(size_t)g * vns + t];
  __syncthreads();
  for (int o = t; o < 512; o += 256) {
    float a = B1[o];
    for (int k = 0; k < 256; k++) a = fmaf(vt[k], W1[k * 512 + o], a);
    u[o] = a > 0 ? a : 0;
  }
  __syncthreads();
  float a = B2[t];
  for (int k = 0; k < 512; k++) a = fmaf(u[k], W2[k * 256 + t], a);
  vn_out[g * 256 + t] = a > 0 ? a : 0;
}

__global__ void k_bnfin(const float* __restrict__ Ssum, const float* __restrict__ Ssq,
                        const float* __restrict__ g, const float* __restrict__ b,
                        float* __restrict__ scale, float* __restrict__ shift,
                        int NC, float invN) {
  int c = blockIdx.x * 256 + threadIdx.x;
  if (c >= NC) return;
  float mu = Ssum[c] * invN;
  float var = Ssq[c] * invN - mu * mu;
  float rs = rsqrtf(var + 1e-5f);
  float s = rs * g[c];
  scale[c] = s;
  shift[c] = b[c] - mu * s;
}

// out = t2*sc[c]+sh[c] (final BN, JK='last', no relu)
__global__ void k_final(const float* __restrict__ T2, const float* __restrict__ sc,
                        const float* __restrict__ sh, float* __restrict__ out) {
  int i = blockIdx.x * 256 + threadIdx.x; // 2097152 float4s
  int c4 = (i & 63) * 4;
  float4 v = *(const float4*)&T2[(size_t)i * 4];
  float4 s4 = *(const float4*)&sc[c4];
  float4 h4 = *(const float4*)&sh[c4];
  v.x = fmaf(v.x, s4.x, h4.x); v.y = fmaf(v.y, s4.y, h4.y);
  v.z = fmaf(v.z, s4.z, h4.z); v.w = fmaf(v.w, s4.w, h4.w);
  *(float4*)&out[(size_t)i * 4] = v;
}

extern "C" void kernel_launch(void* const* d_in, const int* in_sizes, int n_in,
                              void* d_out, int out_size, void* d_ws, size_t ws_size,
                              hipStream_t stream) {
  (void)in_sizes; (void)n_in; (void)out_size; (void)ws_size;
  const int*   atom_idx = (const int*)d_in[0];
  const int*   lei      = (const int*)d_in[1];
  const int*   eattr    = (const int*)d_in[2];
  const float* atom_emb = (const float*)d_in[4];
  const float* bemb_h   = (const float*)d_in[5];
  const float* elw      = (const float*)d_in[6];
  const float* elb      = (const float*)d_in[7];
  const float* bemb_l   = (const float*)d_in[8];
  const float* geps     = (const float*)d_in[9];
  const float* mw1      = (const float*)d_in[10];
  const float* mb1      = (const float*)d_in[11];
  const float* mbng     = (const float*)d_in[12];
  const float* mbnb     = (const float*)d_in[13];
  const float* mw2      = (const float*)d_in[14];
  const float* mb2      = (const float*)d_in[15];
  const float* obng     = (const float*)d_in[16];
  const float* obnb     = (const float*)d_in[17];
  const float* vne      = (const float*)d_in[18];
  const float* vw1      = (const float*)d_in[19];
  const float* vb1      = (const float*)d_in[20];
  const float* vw2      = (const float*)d_in[21];
  const float* vb2      = (const float*)d_in[22];
  float* out = (float*)d_out;

  // ws layout (33.55MB units): A_, X0T, X1T, YT, Z_, tail (~7.1MB)
  float* W   = (float*)d_ws;
  float* A_  = W;
  float* X0T = W + (size_t)FBUF;
  float* X1T = W + (size_t)2 * FBUF;
  float* YT  = W + (size_t)3 * FBUF;
  float* Z_  = W + (size_t)4 * FBUF;
  float* SM  = W + (size_t)5 * FBUF;
  float* EWT = SM;                   // 16
  float* S1S = SM + 256;             // 512
  float* S1Q = SM + 768;             // 512
  float* S2S = SM + 1280;            // 256
  float* S2Q = SM + 1536;            // 256  (S1S..S2Q contiguous 1536)
  float* SC2 = SM + 1792;            // 256
  float* SH2 = SM + 2048;            // 256
  float* VNA = SM + 2304;            // 32768
  float* VNB = SM + 35072;           // 32768
  float* VNT = SM + 67840;           // 32768
  int* ROWPTR = (int*)(SM + 100608); // 32772
  int* POS    = ROWPTR + 32772;      // 32768
  int* COUNTS = POS + 32768;         // 32768
  int* CSR    = COUNTS + 32768;      // 262144
  unsigned short* W1hT = (unsigned short*)(SM + 461312);  // 5*512*256 shorts
  unsigned short* W1lT = (unsigned short*)(SM + 788992);
  unsigned short* W2hT = (unsigned short*)(SM + 1116672); // 5*256*512 shorts
  unsigned short* W2lT = (unsigned short*)(SM + 1444352);
  float* T2 = A_;
  float* H0 = X0T;
  unsigned short* T1h = (unsigned short*)X1T;
  unsigned short* T1l = (unsigned short*)YT;
  unsigned short* Zh  = (unsigned short*)Z_;
  unsigned short* Zl  = Zh + (size_t)NNODE * 256;
  int* PACKED = (int*)Z_;

  // ---- stage 1: dense learned-adjacency propagation (transposed space) ----
  k_zero<<<8192, 256, 0, stream>>>((uint4*)A_, 2097152);
  k_zero<<<8192, 256, 0, stream>>>((uint4*)PACKED, 2097152);
  k_zero<<<32, 256, 0, stream>>>((uint4*)COUNTS, 8192);
  k_ewtbl<<<1, 1024, 0, stream>>>(bemb_h, elw, elb, EWT);
  k_pack_adj<<<NEDGE / 256, 256, 0, stream>>>(lei, eattr, PACKED);
  k_unpack_adj<<<32768, 256, 0, stream>>>(PACKED, EWT, A_);
  k_addeye<<<NNODE / 256, 256, 0, stream>>>(A_);
  k_degnorm<<<B_G, 256, 0, stream>>>(A_);
  // weight transpose+split (once)
  k_wtsplit<<<dim3(8, 4, 5), 256, 0, stream>>>(mw1, W1hT, W1lT, 256, 512, 131072, 131072);
  k_wtsplit<<<dim3(4, 8, 5), 256, 0, stream>>>(mw2, W2hT, W2lT, 512, 256, 131072, 131072);
  k_feaT<<<32768, 256, 0, stream>>>(atom_idx, atom_emb, X0T, YT);
  // order=3: Xt_next = Xt @ A^T (== (A@X)^T), Yt accumulates
  k_mgemm<<<dim3(2, 2, B_G), 256, 0, stream>>>(X0T, A_, X1T, YT, 256, 256, 65536, 65536, 65536);
  k_mgemm<<<dim3(2, 2, B_G), 256, 0, stream>>>(X1T, A_, X0T, YT, 256, 256, 65536, 65536, 65536);
  k_mgemm<<<dim3(2, 2, B_G), 256, 0, stream>>>(X0T, A_, X1T, YT, 256, 256, 65536, 65536, 65536);
  // H0[n][e] = 0.25 * YT[e][n]
  k_transp<<<dim3(4, 4, B_G), 256, 0, stream>>>(YT, H0, 256, 256, 65536, 65536, 0.25f);

  // ---- CSR (once; edges invariant across layers) ----
  k_count<<<NEDGE / 256, 256, 0, stream>>>(lei, COUNTS);
  k_scan<<<B_G, 256, 0, stream>>>(COUNTS, ROWPTR, POS);
  k_fill<<<NEDGE / 256, 256, 0, stream>>>(lei, eattr, POS, CSR);

  // ---- GIN + virtual-node stack ----
  const float* vn_cur = vne; int vns = 0;   // layer0 vn = vn_emb broadcast
  float* vn_next = VNA;
  for (int l = 0; l < NL; l++) {
    const float* hsrc = (l == 0) ? H0 : T2;
    const float* hsc  = (l == 0) ? nullptr : SC2;
    const float* hsh  = (l == 0) ? nullptr : SH2;
    k_zero<<<2, 256, 0, stream>>>((uint4*)S1S, 384);   // S1S,S1Q,S2S,S2Q
    k_zero<<<32, 256, 0, stream>>>((uint4*)VNT, 8192); // vn colsum accumulator
    k_agg<<<NNODE / 4, 256, 0, stream>>>(hsrc, hsc, hsh, vn_cur, vns,
        bemb_l + (size_t)l * 16 * EMB, ROWPTR, CSR, geps, l, Zh, Zl, VNT);
    if (l < NL - 1)
      k_vn<<<B_G, 256, 0, stream>>>(VNT, vn_cur, vns,
          vw1 + (size_t)l * EMB * 512, vb1 + (size_t)l * 512,
          vw2 + (size_t)l * 512 * EMB, vb2 + (size_t)l * EMB, vn_next);
    k_bgemm<<<dim3(4, 256), 256, 0, stream>>>(Zh, Zl,
        W1hT + (size_t)l * 131072, W1lT + (size_t)l * 131072,
        mb1 + (size_t)l * 512, nullptr, T1h, T1l, S1S, S1Q, 256, 512);
    k_bnsplit<<<16384, 256, 0, stream>>>(T1h, T1l, S1S, S1Q,
        mbng + (size_t)l * 512, mbnb + (size_t)l * 512);
    k_bgemm<<<dim3(2, 256), 256, 0, stream>>>(T1h, T1l,
        W2hT + (size_t)l * 131072, W2lT + (size_t)l * 131072,
        mb2 + (size_t)l * 256, T2, nullptr, nullptr, S2S, S2Q, 512, 256);
    k_bnfin<<<1, 256, 0, stream>>>(S2S, S2Q, obng + (size_t)l * EMB,
        obnb + (size_t)l * EMB, SC2, SH2, 256, 1.0f / NNODE);
    if (l < NL - 1) {
      vn_cur = vn_next; vns = EMB;
      vn_next = (vn_next == VNA) ? VNB : VNA;
    }
  }
  k_final<<<8192, 256, 0, stream>>>(T2, SC2, SH2, out);
}

// Round 6
// 1433.169 us; speedup vs baseline: 2.0746x; 2.0746x over previous
//
#include <hip/hip_runtime.h>
#include <math.h>

// GNN_node_Virtualnode: B=128 graphs, 256 nodes/graph, 2048 edges/graph,
// emb=256, 5 GIN layers + virtual node, learned dense-adjacency propagation.
// Round 6: REVERT R5's k_agg atomics+swizzle (7x regression: 256-way atomic
// contention, 164MB write-through). vn colsum via contention-free 2-partial
// reduction (k_vnsum). Keep bgemm 3 blocks/CU (B-lo direct from global).

#define B_G   128
#define NPG   256
#define EPG   2048
#define EMB   256
#define NL    5
#define NNODE (B_G*NPG)   // 32768
#define NEDGE (B_G*EPG)   // 262144
#define FBUF  8388608     // floats per 33.55MB buffer

typedef __attribute__((ext_vector_type(8))) short bf16x8;
typedef __attribute__((ext_vector_type(4))) float f32x4;

// ---------------- helpers ----------------
__device__ __forceinline__ void split1(float x, unsigned short& h, unsigned short& l) {
  // round-to-nearest-even bf16 hi, then bf16(residual)
  unsigned u = __builtin_bit_cast(unsigned, x);
  unsigned hr = u + 0x7FFFu + ((u >> 16) & 1u);
  h = (unsigned short)(hr >> 16);
  float hf = __builtin_bit_cast(float, hr & 0xFFFF0000u);
  float r = x - hf;
  unsigned v = __builtin_bit_cast(unsigned, r);
  unsigned lr = v + 0x7FFFu + ((v >> 16) & 1u);
  l = (unsigned short)(lr >> 16);
}

__device__ __forceinline__ float bdec(unsigned short h) {
  return __builtin_bit_cast(float, (unsigned)h << 16);
}

__device__ __forceinline__ void gload16(unsigned short* lds, const unsigned short* g) {
  // async global->LDS, 16B/lane; LDS dest = wave-uniform base + lane*16
  __builtin_amdgcn_global_load_lds(
      (const __attribute__((address_space(1))) unsigned int*)g,
      (__attribute__((address_space(3))) unsigned int*)lds, 16, 0, 0);
}

__global__ void k_zero(uint4* p, int n16) {
  int i = blockIdx.x * 256 + threadIdx.x;
  if (i < n16) p[i] = make_uint4(0, 0, 0, 0);
}

// 16-entry sigmoid edge-weight table: 16 waves, one per bond value
__global__ void k_ewtbl(const float* __restrict__ bh, const float* __restrict__ w,
                        const float* __restrict__ b, float* __restrict__ tbl) {
  int v = threadIdx.x >> 6, t = threadIdx.x & 63;
  float p = bh[v * 64 + t] * w[t];
  for (int off = 32; off; off >>= 1) p += __shfl_down(p, off, 64);
  if (t == 0) tbl[v] = 1.0f / (1.0f + expf(-(p + b[0])));
}

// Deterministic duplicate resolution: last edge (max e) wins.
__global__ void k_pack_adj(const int* __restrict__ lei, const int* __restrict__ ea,
                           int* __restrict__ packed) {
  int idx = blockIdx.x * 256 + threadIdx.x;       // NEDGE
  int g = idx >> 11, e = idx & 2047;
  int s = lei[g * 4096 + e];
  int d = lei[g * 4096 + 2048 + e];
  int v = ((e + 1) << 4) | ea[g * 2048 + e];
  atomicMax(&packed[g * 65536 + s * 256 + d], v);
}

__global__ void k_unpack_adj(const int* __restrict__ packed,
                             const float* __restrict__ tbl, float* __restrict__ adj) {
  int idx = blockIdx.x * 256 + threadIdx.x;       // 8388608
  int v = packed[idx];
  adj[idx] = v ? tbl[v & 15] : 0.0f;
}

__global__ void k_addeye(float* __restrict__ adj) {
  int idx = blockIdx.x * 256 + threadIdx.x;       // NNODE
  int g = idx >> 8, i = idx & 255;
  adj[g * 65536 + i * 257] += 1.0f;
}

// A[i][j] = colsum(i)^-1/2 * adj[i][j] * rowsum(j)^-1/2  (in place)
__global__ __launch_bounds__(256)
void k_degnorm(float* __restrict__ adj) {
  int g = blockIdx.x, t = threadIdx.x;
  float* Ag = adj + (size_t)g * 65536;
  __shared__ float cs[256];
  float s0 = 0, s1 = 0, s2 = 0, s3 = 0;
  for (int i = 0; i < 256; i += 4) {
    s0 += Ag[(i + 0) * 256 + t]; s1 += Ag[(i + 1) * 256 + t];
    s2 += Ag[(i + 2) * 256 + t]; s3 += Ag[(i + 3) * 256 + t];
  }
  cs[t] = rsqrtf((s0 + s1) + (s2 + s3));          // colsum(t)^-1/2
  float4 r0 = make_float4(0, 0, 0, 0), r1 = r0, r2 = r0, r3 = r0;
  const float4* A4 = (const float4*)(Ag + t * 256);
  for (int j = 0; j < 64; j += 4) {
    float4 v0 = A4[j], v1 = A4[j + 1], v2 = A4[j + 2], v3 = A4[j + 3];
    r0.x += v0.x + v0.y; r0.y += v0.z + v0.w;
    r1.x += v1.x + v1.y; r1.y += v1.z + v1.w;
    r2.x += v2.x + v2.y; r2.y += v2.z + v2.w;
    r3.x += v3.x + v3.y; r3.y += v3.z + v3.w;
  }
  float rc = rsqrtf((r0.x + r0.y) + (r1.x + r1.y) + (r2.x + r2.y) + (r3.x + r3.y));
  __syncthreads();
  for (int i = 0; i < 256; i++) Ag[i * 256 + t] = cs[i] * Ag[i * 256 + t] * rc;
}

// transposed fea gather: X0t[g][e][n] = Yt[g][e][n] = atom_emb[aidx[g*256+n]][e]
__global__ void k_feaT(const int* __restrict__ aidx, const float* __restrict__ aemb,
                       float* __restrict__ X0t, float* __restrict__ Yt) {
  int i = blockIdx.x * 256 + threadIdx.x;          // 8388608
  int g = i >> 16, e = (i >> 8) & 255, n = i & 255;
  int av = aidx[g * 256 + n];
  float v = aemb[av * 256 + e];
  X0t[i] = v; Yt[i] = v;
}

// generic LDS-tiled transpose: dst[z][N][K] = scale * src[z][K][N]
__global__ __launch_bounds__(256)
void k_transp(const float* __restrict__ src, float* __restrict__ dst,
              int K, int N, long ss, long sd, float scale) {
  __shared__ float tl[64][65];
  src += (size_t)blockIdx.z * ss; dst += (size_t)blockIdx.z * sd;
  int n0 = blockIdx.x * 64, k0 = blockIdx.y * 64;
  int t = threadIdx.x;
  int c = (t & 15) * 4, r = t >> 4;
#pragma unroll
  for (int p = 0; p < 4; p++) {
    int rr = r + p * 16;
    float4 v = *(const float4*)&src[(size_t)(k0 + rr) * N + n0 + c];
    tl[rr][c] = v.x; tl[rr][c + 1] = v.y; tl[rr][c + 2] = v.z; tl[rr][c + 3] = v.w;
  }
  __syncthreads();
#pragma unroll
  for (int p = 0; p < 4; p++) {
    int rr = r + p * 16;
    float4 o;
    o.x = tl[c][rr] * scale;     o.y = tl[c + 1][rr] * scale;
    o.z = tl[c + 2][rr] * scale; o.w = tl[c + 3][rr] * scale;
    *(float4*)&dst[(size_t)(n0 + rr) * K + k0 + c] = o;
  }
}

// fused transpose + hi/lo split: dh/dl[z][N][K] = split(src[z][K][N])
__global__ __launch_bounds__(256)
void k_wtsplit(const float* __restrict__ src, unsigned short* __restrict__ dh,
               unsigned short* __restrict__ dl, int K, int N, long ss, long sd) {
  __shared__ float tl[64][65];
  src += (size_t)blockIdx.z * ss;
  dh += (size_t)blockIdx.z * sd; dl += (size_t)blockIdx.z * sd;
  int n0 = blockIdx.x * 64, k0 = blockIdx.y * 64;
  int t = threadIdx.x;
  int c = (t & 15) * 4, r = t >> 4;
#pragma unroll
  for (int p = 0; p < 4; p++) {
    int rr = r + p * 16;
    float4 v = *(const float4*)&src[(size_t)(k0 + rr) * N + n0 + c];
    tl[rr][c] = v.x; tl[rr][c + 1] = v.y; tl[rr][c + 2] = v.z; tl[rr][c + 3] = v.w;
  }
  __syncthreads();
#pragma unroll
  for (int p = 0; p < 4; p++) {
    int rr = r + p * 16;
    ushort4 hh, ll;
    split1(tl[c][rr],     hh.x, ll.x);
    split1(tl[c + 1][rr], hh.y, ll.y);
    split1(tl[c + 2][rr], hh.z, ll.z);
    split1(tl[c + 3][rr], hh.w, ll.w);
    size_t o = (size_t)(n0 + rr) * K + k0 + c;
    *(ushort4*)&dh[o] = hh; *(ushort4*)&dl[o] = ll;
  }
}

// ---- prop GEMM (fp32 inputs, in-kernel split; validated R2 kernel) ----
// C[z][M][N] = A[z][M][K] @ Bt[z][N][K]^T ; optional Yacc += C.
__global__ __launch_bounds__(256, 2)
void k_mgemm(const float* __restrict__ A, const float* __restrict__ Bt,
             float* __restrict__ C, float* __restrict__ Yacc, int K, int N,
             long sA, long sBt, long sC) {
  __shared__ alignas(16) unsigned short Ah[128 * 64], Al[128 * 64];
  __shared__ alignas(16) unsigned short Bh[128 * 64], Bl[128 * 64];
  int z = blockIdx.z;
  A += (size_t)z * sA; Bt += (size_t)z * sBt; C += (size_t)z * sC;
  float* Yp = Yacc ? Yacc + (size_t)z * sC : nullptr;
  int rowbase = blockIdx.y * 128, colbase = blockIdx.x * 128;
  int t = threadIdx.x, l = t & 63, w = t >> 6;
  int wr = w >> 1, wc = w & 1;
  f32x4 acc[4][4];
#pragma unroll
  for (int i = 0; i < 4; i++)
#pragma unroll
    for (int j = 0; j < 4; j++) acc[i][j] = (f32x4){0, 0, 0, 0};

  for (int k0 = 0; k0 < K; k0 += 64) {
    __syncthreads();
    for (int p = 0; p < 8; p++) {
      int flat = p * 256 + t;                    // 0..2047
      int r = flat >> 4, kq = (flat & 15) * 4;   // row 0..127, k-quad
      float4 va = *(const float4*)&A[(size_t)(rowbase + r) * K + k0 + kq];
      int off = ((r * 128 + kq * 2) ^ ((r & 7) << 4)) >> 1;  // short index
      ushort4 hh, ll;
      split1(va.x, hh.x, ll.x); split1(va.y, hh.y, ll.y);
      split1(va.z, hh.z, ll.z); split1(va.w, hh.w, ll.w);
      *(ushort4*)&Ah[off] = hh; *(ushort4*)&Al[off] = ll;
      float4 vb = *(const float4*)&Bt[(size_t)(colbase + r) * K + k0 + kq];
      split1(vb.x, hh.x, ll.x); split1(vb.y, hh.y, ll.y);
      split1(vb.z, hh.z, ll.z); split1(vb.w, hh.w, ll.w);
      *(ushort4*)&Bh[off] = hh; *(ushort4*)&Bl[off] = ll;
    }
    __syncthreads();
#pragma unroll
    for (int ks = 0; ks < 2; ks++) {
      bf16x8 ah[4], al_[4], bh[4], bl[4];
#pragma unroll
      for (int fm = 0; fm < 4; fm++) {
        int r = wr * 64 + fm * 16 + (l & 15);
        int off = (r * 64 + ks * 32 + (l >> 4) * 8) ^ ((r & 7) << 3);
        ah[fm] = *(const bf16x8*)&Ah[off];
        al_[fm] = *(const bf16x8*)&Al[off];
      }
#pragma unroll
      for (int fn = 0; fn < 4; fn++) {
        int c = wc * 64 + fn * 16 + (l & 15);
        int off = (c * 64 + ks * 32 + (l >> 4) * 8) ^ ((c & 7) << 3);
        bh[fn] = *(const bf16x8*)&Bh[off];
        bl[fn] = *(const bf16x8*)&Bl[off];
      }
#pragma unroll
      for (int fm = 0; fm < 4; fm++)
#pragma unroll
        for (int fn = 0; fn < 4; fn++) {
          acc[fm][fn] = __builtin_amdgcn_mfma_f32_16x16x32_bf16(ah[fm], bh[fn], acc[fm][fn], 0, 0, 0);
          acc[fm][fn] = __builtin_amdgcn_mfma_f32_16x16x32_bf16(ah[fm], bl[fn], acc[fm][fn], 0, 0, 0);
          acc[fm][fn] = __builtin_amdgcn_mfma_f32_16x16x32_bf16(al_[fm], bh[fn], acc[fm][fn], 0, 0, 0);
        }
    }
  }
#pragma unroll
  for (int fm = 0; fm < 4; fm++)
#pragma unroll
    for (int r4 = 0; r4 < 4; r4++) {
      int row = rowbase + wr * 64 + fm * 16 + (l >> 4) * 4 + r4;
#pragma unroll
      for (int fn = 0; fn < 4; fn++) {
        int col = colbase + wc * 64 + fn * 16 + (l & 15);
        float v = acc[fm][fn][r4];
        size_t idx = (size_t)row * N + col;
        if (Yp) Yp[idx] += v;
        C[idx] = v;
      }
    }
}

// ---- MLP GEMM: pre-split bf16 hi/lo, global_load_lds staging (Ah/Al/Bh);
// B-lo fragments loaded direct global->VGPR (weights L2-resident).
// 48KB LDS -> 3 blocks/CU. Fused column sum/sumsq. Output fp32 or bf16 pair.
__global__ __launch_bounds__(256, 3)
void k_bgemm(const unsigned short* __restrict__ Ah_g, const unsigned short* __restrict__ Al_g,
             const unsigned short* __restrict__ Bh_g, const unsigned short* __restrict__ Bl_g,
             const float* __restrict__ bias, float* __restrict__ Cf,
             unsigned short* __restrict__ Ch, unsigned short* __restrict__ Cl,
             float* __restrict__ Ssum, float* __restrict__ Ssq, int K, int N) {
  __shared__ alignas(16) unsigned short Ah[128 * 64], Al[128 * 64];
  __shared__ alignas(16) unsigned short Bh[128 * 64];
  int rowbase = blockIdx.y * 128, colbase = blockIdx.x * 128;
  int t = threadIdx.x, l = t & 63, wid = t >> 6;
  int wr = wid >> 1, wc = wid & 1;
  int r8 = l >> 3, cb = (l & 7) * 8;               // staging lane -> (row, col)
  f32x4 acc[4][4];
#pragma unroll
  for (int i = 0; i < 4; i++)
#pragma unroll
    for (int j = 0; j < 4; j++) acc[i][j] = (f32x4){0, 0, 0, 0};

  for (int k0 = 0; k0 < K; k0 += 64) {
    __syncthreads();                               // prior readers done
#pragma unroll
    for (int i = 0; i < 4; i++) {
      int chunk = wid * 4 + i;                     // 0..15 -> 8 rows each
      int row = chunk * 8 + r8;
      size_t goA = (size_t)(rowbase + row) * K + k0 + cb;
      size_t goB = (size_t)(colbase + row) * K + k0 + cb;
      gload16(Ah + chunk * 512, Ah_g + goA);
      gload16(Al + chunk * 512, Al_g + goA);
      gload16(Bh + chunk * 512, Bh_g + goB);
    }
    bf16x8 blr[2][4];                              // B-lo direct from global
#pragma unroll
    for (int ks = 0; ks < 2; ks++)
#pragma unroll
      for (int fn = 0; fn < 4; fn++) {
        int c = colbase + wc * 64 + fn * 16 + (l & 15);
        blr[ks][fn] = *(const bf16x8*)&Bl_g[(size_t)c * K + k0 + ks * 32 + (l >> 4) * 8];
      }
    __syncthreads();                               // vmcnt(0) drain + barrier
#pragma unroll
    for (int ks = 0; ks < 2; ks++) {
      bf16x8 ah[4], al_[4], bh[4];
#pragma unroll
      for (int fm = 0; fm < 4; fm++) {
        int r = wr * 64 + fm * 16 + (l & 15);
        ah[fm]  = *(const bf16x8*)&Ah[r * 64 + ks * 32 + (l >> 4) * 8];
        al_[fm] = *(const bf16x8*)&Al[r * 64 + ks * 32 + (l >> 4) * 8];
      }
#pragma unroll
      for (int fn = 0; fn < 4; fn++) {
        int c = wc * 64 + fn * 16 + (l & 15);
        bh[fn] = *(const bf16x8*)&Bh[c * 64 + ks * 32 + (l >> 4) * 8];
      }
#pragma unroll
      for (int fm = 0; fm < 4; fm++)
#pragma unroll
        for (int fn = 0; fn < 4; fn++) {
          acc[fm][fn] = __builtin_amdgcn_mfma_f32_16x16x32_bf16(ah[fm], bh[fn], acc[fm][fn], 0, 0, 0);
          acc[fm][fn] = __builtin_amdgcn_mfma_f32_16x16x32_bf16(ah[fm], blr[ks][fn], acc[fm][fn], 0, 0, 0);
          acc[fm][fn] = __builtin_amdgcn_mfma_f32_16x16x32_bf16(al_[fm], bh[fn], acc[fm][fn], 0, 0, 0);
        }
    }
  }
  __syncthreads();
  float bi[4], scoll[4] = {0, 0, 0, 0}, qcoll[4] = {0, 0, 0, 0};
#pragma unroll
  for (int fn = 0; fn < 4; fn++)
    bi[fn] = bias ? bias[colbase + wc * 64 + fn * 16 + (l & 15)] : 0.0f;
#pragma unroll
  for (int fm = 0; fm < 4; fm++)
#pragma unroll
    for (int r4 = 0; r4 < 4; r4++) {
      int row = rowbase + wr * 64 + fm * 16 + (l >> 4) * 4 + r4;
#pragma unroll
      for (int fn = 0; fn < 4; fn++) {
        int col = colbase + wc * 64 + fn * 16 + (l & 15);
        float v = acc[fm][fn][r4] + bi[fn];
        size_t idx = (size_t)row * N + col;
        if (Cf) Cf[idx] = v;
        if (Ch) { unsigned short hh, ll; split1(v, hh, ll); Ch[idx] = hh; Cl[idx] = ll; }
        scoll[fn] += v; qcoll[fn] += v * v;
      }
    }
  if (Ssum) {
    float* scr = (float*)Ah;                       // 256 floats scratch
    scr[t] = 0.0f;
    __syncthreads();
#pragma unroll
    for (int fn = 0; fn < 4; fn++) {
      int cl_ = wc * 64 + fn * 16 + (l & 15);
      atomicAdd(&scr[cl_ * 2], scoll[fn]);
      atomicAdd(&scr[cl_ * 2 + 1], qcoll[fn]);
    }
    __syncthreads();
    if (t < 128) {
      atomicAdd(&Ssum[colbase + t], scr[t * 2]);
      atomicAdd(&Ssq[colbase + t], scr[t * 2 + 1]);
    }
  }
}

// in-place BN(+relu) on T1 hi/lo pairs; BN1 finalize fused (reads raw stats)
__global__ void k_bnsplit(unsigned short* __restrict__ Th, unsigned short* __restrict__ Tl,
                          const float* __restrict__ Ssum, const float* __restrict__ Ssq,
                          const float* __restrict__ g, const float* __restrict__ b) {
  size_t i = (size_t)blockIdx.x * 256 + threadIdx.x;  // 4.19M threads x4 elems
  int c4 = ((int)i & 127) * 4;
  ushort4 h4 = *(ushort4*)&Th[i * 4];
  ushort4 l4 = *(ushort4*)&Tl[i * 4];
  float4 ss = *(const float4*)&Ssum[c4], qq = *(const float4*)&Ssq[c4];
  float4 gg = *(const float4*)&g[c4],    bb = *(const float4*)&b[c4];
  const float invN = 1.0f / 32768.0f;
  float x, mu, var, sc, sh;
#define BNS(cmp) \
  mu = ss.cmp * invN; var = qq.cmp * invN - mu * mu; \
  sc = rsqrtf(var + 1e-5f) * gg.cmp; sh = bb.cmp - mu * sc; \
  x = bdec(h4.cmp) + bdec(l4.cmp); x = fmaf(x, sc, sh); x = x > 0 ? x : 0; \
  split1(x, h4.cmp, l4.cmp);
  BNS(x) BNS(y) BNS(z) BNS(w)
#undef BNS
  *(ushort4*)&Th[i * 4] = h4;
  *(ushort4*)&Tl[i * 4] = l4;
}

// ---- CSR build (edge structure is layer-invariant; built once) ----
__global__ void k_count(const int* __restrict__ lei, int* __restrict__ counts) {
  int idx = blockIdx.x * 256 + threadIdx.x;
  int g = idx >> 11, e = idx & 2047;
  int d = lei[g * 4096 + 2048 + e];
  atomicAdd(&counts[g * 256 + d], 1);
}

__global__ void k_scan(const int* __restrict__ counts, int* __restrict__ rowptr,
                       int* __restrict__ pos) {
  int g = blockIdx.x, t = threadIdx.x;
  __shared__ int sc[256];
  int own = counts[g * 256 + t];
  sc[t] = own;
  __syncthreads();
  for (int off = 1; off < 256; off <<= 1) {
    int v = 0;
    if (t >= off) v = sc[t - off];
    __syncthreads();
    sc[t] += v;
    __syncthreads();
  }
  int val = g * 2048 + sc[t] - own; // exclusive
  rowptr[g * 256 + t] = val;
  pos[g * 256 + t] = val;
  if (g == B_G - 1 && t == 255) rowptr[B_G * 256] = B_G * 2048;
}

__global__ void k_fill(const int* __restrict__ lei, const int* __restrict__ ea,
                       int* __restrict__ pos, int* __restrict__ csr) {
  int idx = blockIdx.x * 256 + threadIdx.x;
  int g = idx >> 11, e = idx & 2047;
  int s = lei[g * 4096 + e];
  int d = lei[g * 4096 + 2048 + e];
  int eav = ea[g * 2048 + e];
  int slot = atomicAdd(&pos[g * 256 + d], 1);
  csr[slot] = s | (eav << 16);
}

// z = (1+eps)*(h+vn) + sum_{e->this} relu(h[src]+vn+eemb[ea]); out bf16 pair
__global__ __launch_bounds__(256)
void k_agg(const float* __restrict__ H,
           const float* __restrict__ hsc, const float* __restrict__ hsh,
           const float* __restrict__ vn, int vns,
           const float* __restrict__ eemb,
           const int* __restrict__ rowptr, const int* __restrict__ csr,
           const float* __restrict__ geps, int l,
           unsigned short* __restrict__ Zh, unsigned short* __restrict__ Zl) {
  __shared__ float ee[16 * 256];
  for (int i = threadIdx.x; i < 4096; i += 256) ee[i] = eemb[i];
  __syncthreads();
  int lane = threadIdx.x & 63, w = threadIdx.x >> 6;
  int m = blockIdx.x * 4 + w;
  int g = m >> 8;
  int d = lane * 4;
  float eps1 = 1.0f + geps[l];
  float4 sc4 = make_float4(0, 0, 0, 0), sh4 = make_float4(0, 0, 0, 0);
  if (hsc) { sc4 = *(const float4*)&hsc[d]; sh4 = *(const float4*)&hsh[d]; }
  float4 vn4 = *(const float4*)&vn[(size_t)g * vns + d];
  int rp = rowptr[m], rp1 = rowptr[m + 1];
  float4 acc = make_float4(0, 0, 0, 0);
  int gbase = g << 8;
  for (int j = rp; j < rp1; j++) {
    int cw = csr[j];
    int src = cw & 0xFFFF, eav = cw >> 16;
    float4 h4 = *(const float4*)&H[(size_t)(gbase + src) * 256 + d];
    if (hsc) {
      h4.x = fmaf(h4.x, sc4.x, sh4.x); h4.y = fmaf(h4.y, sc4.y, sh4.y);
      h4.z = fmaf(h4.z, sc4.z, sh4.z); h4.w = fmaf(h4.w, sc4.w, sh4.w);
      h4.x = h4.x > 0 ? h4.x : 0; h4.y = h4.y > 0 ? h4.y : 0;
      h4.z = h4.z > 0 ? h4.z : 0; h4.w = h4.w > 0 ? h4.w : 0;
    }
    const float4 e4 = *(const float4*)&ee[eav * 256 + d];
    float mx = h4.x + vn4.x + e4.x; float my = h4.y + vn4.y + e4.y;
    float mz = h4.z + vn4.z + e4.z; float mw = h4.w + vn4.w + e4.w;
    acc.x += mx > 0 ? mx : 0; acc.y += my > 0 ? my : 0;
    acc.z += mz > 0 ? mz : 0; acc.w += mw > 0 ? mw : 0;
  }
  float4 hs = *(const float4*)&H[(size_t)m * 256 + d];
  if (hsc) {
    hs.x = fmaf(hs.x, sc4.x, sh4.x); hs.y = fmaf(hs.y, sc4.y, sh4.y);
    hs.z = fmaf(hs.z, sc4.z, sh4.z); hs.w = fmaf(hs.w, sc4.w, sh4.w);
    hs.x = hs.x > 0 ? hs.x : 0; hs.y = hs.y > 0 ? hs.y : 0;
    hs.z = hs.z > 0 ? hs.z : 0; hs.w = hs.w > 0 ? hs.w : 0;
  }
  float4 z4;
  z4.x = eps1 * (hs.x + vn4.x) + acc.x;
  z4.y = eps1 * (hs.y + vn4.y) + acc.y;
  z4.z = eps1 * (hs.z + vn4.z) + acc.z;
  z4.w = eps1 * (hs.w + vn4.w) + acc.w;
  ushort4 hh, ll;
  split1(z4.x, hh.x, ll.x); split1(z4.y, hh.y, ll.y);
  split1(z4.z, hh.z, ll.z); split1(z4.w, hh.w, ll.w);
  *(ushort4*)&Zh[(size_t)m * 256 + d] = hh;
  *(ushort4*)&Zl[(size_t)m * 256 + d] = ll;
}

// contention-free partial colsums of transformed h: VNP[p][g][256], p in {0,1}
__global__ __launch_bounds__(256)
void k_vnsum(const float* __restrict__ H,
             const float* __restrict__ hsc, const float* __restrict__ hsh,
             float* __restrict__ VNP) {
  int g = blockIdx.x >> 1, p = blockIdx.x & 1, t = threadIdx.x;
  float sc = 0, sh = 0;
  if (hsc) { sc = hsc[t]; sh = hsh[t]; }
  int base = g * 256 + p * 128;
  float s0 = 0, s1 = 0, s2 = 0, s3 = 0;           // 4-deep ILP
  for (int i = 0; i < 128; i += 4) {
    float v0 = H[(size_t)(base + i + 0) * 256 + t];
    float v1 = H[(size_t)(base + i + 1) * 256 + t];
    float v2 = H[(size_t)(base + i + 2) * 256 + t];
    float v3 = H[(size_t)(base + i + 3) * 256 + t];
    if (hsc) {
      v0 = fmaf(v0, sc, sh); v0 = v0 > 0 ? v0 : 0;
      v1 = fmaf(v1, sc, sh); v1 = v1 > 0 ? v1 : 0;
      v2 = fmaf(v2, sc, sh); v2 = v2 > 0 ? v2 : 0;
      v3 = fmaf(v3, sc, sh); v3 = v3 > 0 ? v3 : 0;
    }
    s0 += v0; s1 += v1; s2 += v2; s3 += v3;
  }
  VNP[(size_t)(p * 128 + g) * 256 + t] = (s0 + s1) + (s2 + s3);
}

// vn_out = relu(relu(vt@W1+B1)@W2+B2), vt = VNP[0][g]+VNP[1][g] + 257*vn
__global__ __launch_bounds__(256)
void k_vn(const float* __restrict__ VNP,
          const float* __restrict__ vn_in, int vns,
          const float* __restrict__ W1, const float* __restrict__ B1,
          const float* __restrict__ W2, const float* __restrict__ B2,
          float* __restrict__ vn_out) {
  int g = blockIdx.x, t = threadIdx.x;
  __shared__ float vt[256];
  __shared__ float u[512];
  vt[t] = VNP[(size_t)g * 256 + t] + VNP[(size_t)(128 + g) * 256 + t]
        + 257.0f * vn_in[(size_t)g * vns + t];
  __syncthreads();
  for (int o = t; o < 512; o += 256) {
    float a = B1[o];
    for (int k = 0; k < 256; k++) a = fmaf(vt[k], W1[k * 512 + o], a);
    u[o] = a > 0 ? a : 0;
  }
  __syncthreads();
  float a = B2[t];
  for (int k = 0; k < 512; k++) a = fmaf(u[k], W2[k * 256 + t], a);
  vn_out[g * 256 + t] = a > 0 ? a : 0;
}

__global__ void k_bnfin(const float* __restrict__ Ssum, const float* __restrict__ Ssq,
                        const float* __restrict__ g, const float* __restrict__ b,
                        float* __restrict__ scale, float* __restrict__ shift,
                        int NC, float invN) {
  int c = blockIdx.x * 256 + threadIdx.x;
  if (c >= NC) return;
  float mu = Ssum[c] * invN;
  float var = Ssq[c] * invN - mu * mu;
  float rs = rsqrtf(var + 1e-5f);
  float s = rs * g[c];
  scale[c] = s;
  shift[c] = b[c] - mu * s;
}

// out = t2*sc[c]+sh[c] (final BN, JK='last', no relu)
__global__ void k_final(const float* __restrict__ T2, const float* __restrict__ sc,
                        const float* __restrict__ sh, float* __restrict__ out) {
  int i = blockIdx.x * 256 + threadIdx.x; // 2097152 float4s
  int c4 = (i & 63) * 4;
  float4 v = *(const float4*)&T2[(size_t)i * 4];
  float4 s4 = *(const float4*)&sc[c4];
  float4 h4 = *(const float4*)&sh[c4];
  v.x = fmaf(v.x, s4.x, h4.x); v.y = fmaf(v.y, s4.y, h4.y);
  v.z = fmaf(v.z, s4.z, h4.z); v.w = fmaf(v.w, s4.w, h4.w);
  *(float4*)&out[(size_t)i * 4] = v;
}

extern "C" void kernel_launch(void* const* d_in, const int* in_sizes, int n_in,
                              void* d_out, int out_size, void* d_ws, size_t ws_size,
                              hipStream_t stream) {
  (void)in_sizes; (void)n_in; (void)out_size; (void)ws_size;
  const int*   atom_idx = (const int*)d_in[0];
  const int*   lei      = (const int*)d_in[1];
  const int*   eattr    = (const int*)d_in[2];
  const float* atom_emb = (const float*)d_in[4];
  const float* bemb_h   = (const float*)d_in[5];
  const float* elw      = (const float*)d_in[6];
  const float* elb      = (const float*)d_in[7];
  const float* bemb_l   = (const float*)d_in[8];
  const float* geps     = (const float*)d_in[9];
  const float* mw1      = (const float*)d_in[10];
  const float* mb1      = (const float*)d_in[11];
  const float* mbng     = (const float*)d_in[12];
  const float* mbnb     = (const float*)d_in[13];
  const float* mw2      = (const float*)d_in[14];
  const float* mb2      = (const float*)d_in[15];
  const float* obng     = (const float*)d_in[16];
  const float* obnb     = (const float*)d_in[17];
  const float* vne      = (const float*)d_in[18];
  const float* vw1      = (const float*)d_in[19];
  const float* vb1      = (const float*)d_in[20];
  const float* vw2      = (const float*)d_in[21];
  const float* vb2      = (const float*)d_in[22];
  float* out = (float*)d_out;

  // ws layout (33.55MB units): A_, X0T, X1T, YT, Z_, tail (~6.5MB)
  float* W   = (float*)d_ws;
  float* A_  = W;
  float* X0T = W + (size_t)FBUF;
  float* X1T = W + (size_t)2 * FBUF;
  float* YT  = W + (size_t)3 * FBUF;
  float* Z_  = W + (size_t)4 * FBUF;
  float* SM  = W + (size_t)5 * FBUF;
  float* EWT = SM;                   // 16
  float* S1S = SM + 256;             // 512
  float* S1Q = SM + 768;             // 512
  float* S2S = SM + 1280;            // 256
  float* S2Q = SM + 1536;            // 256  (S1S..S2Q contiguous 1536)
  float* SC2 = SM + 1792;            // 256
  float* SH2 = SM + 2048;            // 256
  float* VNA = SM + 2304;            // 32768
  float* VNB = SM + 35072;           // 32768
  int* ROWPTR = (int*)(SM + 67840);  // 32772
  int* POS    = ROWPTR + 32772;      // 32768
  int* COUNTS = POS + 32768;         // 32768
  int* CSR    = COUNTS + 32768;      // 262144
  unsigned short* W1hT = (unsigned short*)(SM + 428544);  // 5*512*256 shorts
  unsigned short* W1lT = (unsigned short*)(SM + 756224);
  unsigned short* W2hT = (unsigned short*)(SM + 1083904); // 5*256*512 shorts
  unsigned short* W2lT = (unsigned short*)(SM + 1411584);
  float* T2 = A_;
  float* H0 = X0T;
  unsigned short* T1h = (unsigned short*)X1T;
  unsigned short* T1l = (unsigned short*)YT;
  unsigned short* Zh  = (unsigned short*)Z_;
  unsigned short* Zl  = Zh + (size_t)NNODE * 256;
  int* PACKED = (int*)Z_;
  float* VNP  = (float*)POS;         // [2][128][256]; POS/COUNTS dead after CSR build

  // ---- stage 1: dense learned-adjacency propagation (transposed space) ----
  k_zero<<<8192, 256, 0, stream>>>((uint4*)A_, 2097152);
  k_zero<<<8192, 256, 0, stream>>>((uint4*)PACKED, 2097152);
  k_zero<<<32, 256, 0, stream>>>((uint4*)COUNTS, 8192);
  k_ewtbl<<<1, 1024, 0, stream>>>(bemb_h, elw, elb, EWT);
  k_pack_adj<<<NEDGE / 256, 256, 0, stream>>>(lei, eattr, PACKED);
  k_unpack_adj<<<32768, 256, 0, stream>>>(PACKED, EWT, A_);
  k_addeye<<<NNODE / 256, 256, 0, stream>>>(A_);
  k_degnorm<<<B_G, 256, 0, stream>>>(A_);
  // weight transpose+split (once)
  k_wtsplit<<<dim3(8, 4, 5), 256, 0, stream>>>(mw1, W1hT, W1lT, 256, 512, 131072, 131072);
  k_wtsplit<<<dim3(4, 8, 5), 256, 0, stream>>>(mw2, W2hT, W2lT, 512, 256, 131072, 131072);
  k_feaT<<<32768, 256, 0, stream>>>(atom_idx, atom_emb, X0T, YT);
  // order=3: Xt_next = Xt @ A^T (== (A@X)^T), Yt accumulates
  k_mgemm<<<dim3(2, 2, B_G), 256, 0, stream>>>(X0T, A_, X1T, YT, 256, 256, 65536, 65536, 65536);
  k_mgemm<<<dim3(2, 2, B_G), 256, 0, stream>>>(X1T, A_, X0T, YT, 256, 256, 65536, 65536, 65536);
  k_mgemm<<<dim3(2, 2, B_G), 256, 0, stream>>>(X0T, A_, X1T, YT, 256, 256, 65536, 65536, 65536);
  // H0[n][e] = 0.25 * YT[e][n]
  k_transp<<<dim3(4, 4, B_G), 256, 0, stream>>>(YT, H0, 256, 256, 65536, 65536, 0.25f);

  // ---- CSR (once; edges invariant across layers) ----
  k_count<<<NEDGE / 256, 256, 0, stream>>>(lei, COUNTS);
  k_scan<<<B_G, 256, 0, stream>>>(COUNTS, ROWPTR, POS);
  k_fill<<<NEDGE / 256, 256, 0, stream>>>(lei, eattr, POS, CSR);

  // ---- GIN + virtual-node stack ----
  const float* vn_cur = vne; int vns = 0;   // layer0 vn = vn_emb broadcast
  float* vn_next = VNA;
  for (int l = 0; l < NL; l++) {
    const float* hsrc = (l == 0) ? H0 : T2;
    const float* hsc  = (l == 0) ? nullptr : SC2;
    const float* hsh  = (l == 0) ? nullptr : SH2;
    k_agg<<<NNODE / 4, 256, 0, stream>>>(hsrc, hsc, hsh, vn_cur, vns,
        bemb_l + (size_t)l * 16 * EMB, ROWPTR, CSR, geps, l, Zh, Zl);
    if (l < NL - 1) {
      k_vnsum<<<256, 256, 0, stream>>>(hsrc, hsc, hsh, VNP);
      k_vn<<<B_G, 256, 0, stream>>>(VNP, vn_cur, vns,
          vw1 + (size_t)l * EMB * 512, vb1 + (size_t)l * 512,
          vw2 + (size_t)l * 512 * EMB, vb2 + (size_t)l * EMB, vn_next);
    }
    k_zero<<<2, 256, 0, stream>>>((uint4*)S1S, 384);   // S1S,S1Q,S2S,S2Q
    k_bgemm<<<dim3(4, 256), 256, 0, stream>>>(Zh, Zl,
        W1hT + (size_t)l * 131072, W1lT + (size_t)l * 131072,
        mb1 + (size_t)l * 512, nullptr, T1h, T1l, S1S, S1Q, 256, 512);
    k_bnsplit<<<16384, 256, 0, stream>>>(T1h, T1l, S1S, S1Q,
        mbng + (size_t)l * 512, mbnb + (size_t)l * 512);
    k_bgemm<<<dim3(2, 256), 256, 0, stream>>>(T1h, T1l,
        W2hT + (size_t)l * 131072, W2lT + (size_t)l * 131072,
        mb2 + (size_t)l * 256, T2, nullptr, nullptr, S2S, S2Q, 512, 256);
    k_bnfin<<<1, 256, 0, stream>>>(S2S, S2Q, obng + (size_t)l * EMB,
        obnb + (size_t)l * EMB, SC2, SH2, 256, 1.0f / NNODE);
    if (l < NL - 1) {
      vn_cur = vn_next; vns = EMB;
      vn_next = (vn_next == VNA) ? VNB : VNA;
    }
  }
  k_final<<<8192, 256, 0, stream>>>(T2, SC2, SH2, out);
}

// Round 8
// 1197.353 us; speedup vs baseline: 2.4831x; 1.1969x over previous
//
#include <hip/hip_runtime.h>
#include <math.h>

// GNN_node_Virtualnode: B=128 graphs, 256 nodes/graph, 2048 edges/graph,
// emb=256, 5 GIN layers + virtual node, learned dense-adjacency propagation.
// Round 7 (resubmit; prior bench was an infra failure): MLP path pure bf16
// (tolerance is 0.03125 absolute; split was over-engineered): 1 MFMA/frag,
// half the bytes end-to-end. Prop keeps validated 3-term split kernel.

#define B_G   128
#define NPG   256
#define EPG   2048
#define EMB   256
#define NL    5
#define NNODE (B_G*NPG)   // 32768
#define NEDGE (B_G*EPG)   // 262144
#define FBUF  8388608     // floats per 33.55MB buffer

typedef __attribute__((ext_vector_type(8))) short bf16x8;
typedef __attribute__((ext_vector_type(4))) float f32x4;

// ---------------- helpers ----------------
__device__ __forceinline__ void split1(float x, unsigned short& h, unsigned short& l) {
  // round-to-nearest-even bf16 hi, then bf16(residual)
  unsigned u = __builtin_bit_cast(unsigned, x);
  unsigned hr = u + 0x7FFFu + ((u >> 16) & 1u);
  h = (unsigned short)(hr >> 16);
  float hf = __builtin_bit_cast(float, hr & 0xFFFF0000u);
  float r = x - hf;
  unsigned v = __builtin_bit_cast(unsigned, r);
  unsigned lr = v + 0x7FFFu + ((v >> 16) & 1u);
  l = (unsigned short)(lr >> 16);
}

__device__ __forceinline__ unsigned short round1(float x) {
  // round-to-nearest-even bf16
  unsigned u = __builtin_bit_cast(unsigned, x);
  return (unsigned short)((u + 0x7FFFu + ((u >> 16) & 1u)) >> 16);
}

__device__ __forceinline__ float bdec(unsigned short h) {
  return __builtin_bit_cast(float, (unsigned)h << 16);
}

__device__ __forceinline__ void gload16(unsigned short* lds, const unsigned short* g) {
  // async global->LDS, 16B/lane; LDS dest = wave-uniform base + lane*16
  __builtin_amdgcn_global_load_lds(
      (const __attribute__((address_space(1))) unsigned int*)g,
      (__attribute__((address_space(3))) unsigned int*)lds, 16, 0, 0);
}

__global__ void k_zero(uint4* p, int n16) {
  int i = blockIdx.x * 256 + threadIdx.x;
  if (i < n16) p[i] = make_uint4(0, 0, 0, 0);
}

// 16-entry sigmoid edge-weight table: 16 waves, one per bond value
__global__ void k_ewtbl(const float* __restrict__ bh, const float* __restrict__ w,
                        const float* __restrict__ b, float* __restrict__ tbl) {
  int v = threadIdx.x >> 6, t = threadIdx.x & 63;
  float p = bh[v * 64 + t] * w[t];
  for (int off = 32; off; off >>= 1) p += __shfl_down(p, off, 64);
  if (t == 0) tbl[v] = 1.0f / (1.0f + expf(-(p + b[0])));
}

// Deterministic duplicate resolution: last edge (max e) wins.
__global__ void k_pack_adj(const int* __restrict__ lei, const int* __restrict__ ea,
                           int* __restrict__ packed) {
  int idx = blockIdx.x * 256 + threadIdx.x;       // NEDGE
  int g = idx >> 11, e = idx & 2047;
  int s = lei[g * 4096 + e];
  int d = lei[g * 4096 + 2048 + e];
  int v = ((e + 1) << 4) | ea[g * 2048 + e];
  atomicMax(&packed[g * 65536 + s * 256 + d], v);
}

__global__ void k_unpack_adj(const int* __restrict__ packed,
                             const float* __restrict__ tbl, float* __restrict__ adj) {
  int idx = blockIdx.x * 256 + threadIdx.x;       // 8388608
  int v = packed[idx];
  adj[idx] = v ? tbl[v & 15] : 0.0f;
}

__global__ void k_addeye(float* __restrict__ adj) {
  int idx = blockIdx.x * 256 + threadIdx.x;       // NNODE
  int g = idx >> 8, i = idx & 255;
  adj[g * 65536 + i * 257] += 1.0f;
}

// A[i][j] = colsum(i)^-1/2 * adj[i][j] * rowsum(j)^-1/2  (in place)
__global__ __launch_bounds__(256)
void k_degnorm(float* __restrict__ adj) {
  int g = blockIdx.x, t = threadIdx.x;
  float* Ag = adj + (size_t)g * 65536;
  __shared__ float cs[256];
  float s0 = 0, s1 = 0, s2 = 0, s3 = 0;
  for (int i = 0; i < 256; i += 4) {
    s0 += Ag[(i + 0) * 256 + t]; s1 += Ag[(i + 1) * 256 + t];
    s2 += Ag[(i + 2) * 256 + t]; s3 += Ag[(i + 3) * 256 + t];
  }
  cs[t] = rsqrtf((s0 + s1) + (s2 + s3));          // colsum(t)^-1/2
  float4 r0 = make_float4(0, 0, 0, 0), r1 = r0, r2 = r0, r3 = r0;
  const float4* A4 = (const float4*)(Ag + t * 256);
  for (int j = 0; j < 64; j += 4) {
    float4 v0 = A4[j], v1 = A4[j + 1], v2 = A4[j + 2], v3 = A4[j + 3];
    r0.x += v0.x + v0.y; r0.y += v0.z + v0.w;
    r1.x += v1.x + v1.y; r1.y += v1.z + v1.w;
    r2.x += v2.x + v2.y; r2.y += v2.z + v2.w;
    r3.x += v3.x + v3.y; r3.y += v3.z + v3.w;
  }
  float rc = rsqrtf((r0.x + r0.y) + (r1.x + r1.y) + (r2.x + r2.y) + (r3.x + r3.y));
  __syncthreads();
  for (int i = 0; i < 256; i++) Ag[i * 256 + t] = cs[i] * Ag[i * 256 + t] * rc;
}

// transposed fea gather: X0t[g][e][n] = Yt[g][e][n] = atom_emb[aidx[g*256+n]][e]
__global__ void k_feaT(const int* __restrict__ aidx, const float* __restrict__ aemb,
                       float* __restrict__ X0t, float* __restrict__ Yt) {
  int i = blockIdx.x * 256 + threadIdx.x;          // 8388608
  int g = i >> 16, e = (i >> 8) & 255, n = i & 255;
  int av = aidx[g * 256 + n];
  float v = aemb[av * 256 + e];
  X0t[i] = v; Yt[i] = v;
}

// generic LDS-tiled transpose: dst[z][N][K] = scale * src[z][K][N]
__global__ __launch_bounds__(256)
void k_transp(const float* __restrict__ src, float* __restrict__ dst,
              int K, int N, long ss, long sd, float scale) {
  __shared__ float tl[64][65];
  src += (size_t)blockIdx.z * ss; dst += (size_t)blockIdx.z * sd;
  int n0 = blockIdx.x * 64, k0 = blockIdx.y * 64;
  int t = threadIdx.x;
  int c = (t & 15) * 4, r = t >> 4;
#pragma unroll
  for (int p = 0; p < 4; p++) {
    int rr = r + p * 16;
    float4 v = *(const float4*)&src[(size_t)(k0 + rr) * N + n0 + c];
    tl[rr][c] = v.x; tl[rr][c + 1] = v.y; tl[rr][c + 2] = v.z; tl[rr][c + 3] = v.w;
  }
  __syncthreads();
#pragma unroll
  for (int p = 0; p < 4; p++) {
    int rr = r + p * 16;
    float4 o;
    o.x = tl[c][rr] * scale;     o.y = tl[c + 1][rr] * scale;
    o.z = tl[c + 2][rr] * scale; o.w = tl[c + 3][rr] * scale;
    *(float4*)&dst[(size_t)(n0 + rr) * K + k0 + c] = o;
  }
}

// fused transpose + hi/lo split: dh/dl[z][N][K] = split(src[z][K][N])
__global__ __launch_bounds__(256)
void k_wtsplit(const float* __restrict__ src, unsigned short* __restrict__ dh,
               unsigned short* __restrict__ dl, int K, int N, long ss, long sd) {
  __shared__ float tl[64][65];
  src += (size_t)blockIdx.z * ss;
  dh += (size_t)blockIdx.z * sd; dl += (size_t)blockIdx.z * sd;
  int n0 = blockIdx.x * 64, k0 = blockIdx.y * 64;
  int t = threadIdx.x;
  int c = (t & 15) * 4, r = t >> 4;
#pragma unroll
  for (int p = 0; p < 4; p++) {
    int rr = r + p * 16;
    float4 v = *(const float4*)&src[(size_t)(k0 + rr) * N + n0 + c];
    tl[rr][c] = v.x; tl[rr][c + 1] = v.y; tl[rr][c + 2] = v.z; tl[rr][c + 3] = v.w;
  }
  __syncthreads();
#pragma unroll
  for (int p = 0; p < 4; p++) {
    int rr = r + p * 16;
    ushort4 hh, ll;
    split1(tl[c][rr],     hh.x, ll.x);
    split1(tl[c + 1][rr], hh.y, ll.y);
    split1(tl[c + 2][rr], hh.z, ll.z);
    split1(tl[c + 3][rr], hh.w, ll.w);
    size_t o = (size_t)(n0 + rr) * K + k0 + c;
    *(ushort4*)&dh[o] = hh; *(ushort4*)&dl[o] = ll;
  }
}

// ---- prop GEMM (fp32 inputs, in-kernel split; validated R2 kernel) ----
// C[z][M][N] = A[z][M][K] @ Bt[z][N][K]^T ; optional Yacc += C.
__global__ __launch_bounds__(256, 2)
void k_mgemm(const float* __restrict__ A, const float* __restrict__ Bt,
             float* __restrict__ C, float* __restrict__ Yacc, int K, int N,
             long sA, long sBt, long sC) {
  __shared__ alignas(16) unsigned short Ah[128 * 64], Al[128 * 64];
  __shared__ alignas(16) unsigned short Bh[128 * 64], Bl[128 * 64];
  int z = blockIdx.z;
  A += (size_t)z * sA; Bt += (size_t)z * sBt; C += (size_t)z * sC;
  float* Yp = Yacc ? Yacc + (size_t)z * sC : nullptr;
  int rowbase = blockIdx.y * 128, colbase = blockIdx.x * 128;
  int t = threadIdx.x, l = t & 63, w = t >> 6;
  int wr = w >> 1, wc = w & 1;
  f32x4 acc[4][4];
#pragma unroll
  for (int i = 0; i < 4; i++)
#pragma unroll
    for (int j = 0; j < 4; j++) acc[i][j] = (f32x4){0, 0, 0, 0};

  for (int k0 = 0; k0 < K; k0 += 64) {
    __syncthreads();
    for (int p = 0; p < 8; p++) {
      int flat = p * 256 + t;                    // 0..2047
      int r = flat >> 4, kq = (flat & 15) * 4;   // row 0..127, k-quad
      float4 va = *(const float4*)&A[(size_t)(rowbase + r) * K + k0 + kq];
      int off = ((r * 128 + kq * 2) ^ ((r & 7) << 4)) >> 1;  // short index
      ushort4 hh, ll;
      split1(va.x, hh.x, ll.x); split1(va.y, hh.y, ll.y);
      split1(va.z, hh.z, ll.z); split1(va.w, hh.w, ll.w);
      *(ushort4*)&Ah[off] = hh; *(ushort4*)&Al[off] = ll;
      float4 vb = *(const float4*)&Bt[(size_t)(colbase + r) * K + k0 + kq];
      split1(vb.x, hh.x, ll.x); split1(vb.y, hh.y, ll.y);
      split1(vb.z, hh.z, ll.z); split1(vb.w, hh.w, ll.w);
      *(ushort4*)&Bh[off] = hh; *(ushort4*)&Bl[off] = ll;
    }
    __syncthreads();
#pragma unroll
    for (int ks = 0; ks < 2; ks++) {
      bf16x8 ah[4], al_[4], bh[4], bl[4];
#pragma unroll
      for (int fm = 0; fm < 4; fm++) {
        int r = wr * 64 + fm * 16 + (l & 15);
        int off = (r * 64 + ks * 32 + (l >> 4) * 8) ^ ((r & 7) << 3);
        ah[fm] = *(const bf16x8*)&Ah[off];
        al_[fm] = *(const bf16x8*)&Al[off];
      }
#pragma unroll
      for (int fn = 0; fn < 4; fn++) {
        int c = wc * 64 + fn * 16 + (l & 15);
        int off = (c * 64 + ks * 32 + (l >> 4) * 8) ^ ((c & 7) << 3);
        bh[fn] = *(const bf16x8*)&Bh[off];
        bl[fn] = *(const bf16x8*)&Bl[off];
      }
#pragma unroll
      for (int fm = 0; fm < 4; fm++)
#pragma unroll
        for (int fn = 0; fn < 4; fn++) {
          acc[fm][fn] = __builtin_amdgcn_mfma_f32_16x16x32_bf16(ah[fm], bh[fn], acc[fm][fn], 0, 0, 0);
          acc[fm][fn] = __builtin_amdgcn_mfma_f32_16x16x32_bf16(ah[fm], bl[fn], acc[fm][fn], 0, 0, 0);
          acc[fm][fn] = __builtin_amdgcn_mfma_f32_16x16x32_bf16(al_[fm], bh[fn], acc[fm][fn], 0, 0, 0);
        }
    }
  }
#pragma unroll
  for (int fm = 0; fm < 4; fm++)
#pragma unroll
    for (int r4 = 0; r4 < 4; r4++) {
      int row = rowbase + wr * 64 + fm * 16 + (l >> 4) * 4 + r4;
#pragma unroll
      for (int fn = 0; fn < 4; fn++) {
        int col = colbase + wc * 64 + fn * 16 + (l & 15);
        float v = acc[fm][fn][r4];
        size_t idx = (size_t)row * N + col;
        if (Yp) Yp[idx] += v;
        C[idx] = v;
      }
    }
}

// ---- MLP GEMM, pure bf16: C = A @ B^T + bias; A[M][K], B[N][K] bf16.
// 32KB LDS, global_load_lds staging. Fused column sum/sumsq.
// Output: fp32 Cf OR bf16 Ch.
__global__ __launch_bounds__(256, 4)
void k_bgemm(const unsigned short* __restrict__ A_g, const unsigned short* __restrict__ B_g,
             const float* __restrict__ bias, float* __restrict__ Cf,
             unsigned short* __restrict__ Ch,
             float* __restrict__ Ssum, float* __restrict__ Ssq, int K, int N) {
  __shared__ alignas(16) unsigned short As[128 * 64];
  __shared__ alignas(16) unsigned short Bs[128 * 64];
  int rowbase = blockIdx.y * 128, colbase = blockIdx.x * 128;
  int t = threadIdx.x, l = t & 63, wid = t >> 6;
  int wr = wid >> 1, wc = wid & 1;
  int r8 = l >> 3, cb = (l & 7) * 8;               // staging lane -> (row, col)
  f32x4 acc[4][4];
#pragma unroll
  for (int i = 0; i < 4; i++)
#pragma unroll
    for (int j = 0; j < 4; j++) acc[i][j] = (f32x4){0, 0, 0, 0};

  for (int k0 = 0; k0 < K; k0 += 64) {
    __syncthreads();                               // prior readers done
#pragma unroll
    for (int i = 0; i < 4; i++) {
      int chunk = wid * 4 + i;                     // 0..15 -> 8 rows each
      int row = chunk * 8 + r8;
      gload16(As + chunk * 512, A_g + (size_t)(rowbase + row) * K + k0 + cb);
      gload16(Bs + chunk * 512, B_g + (size_t)(colbase + row) * K + k0 + cb);
    }
    __syncthreads();                               // vmcnt(0) drain + barrier
#pragma unroll
    for (int ks = 0; ks < 2; ks++) {
      bf16x8 ah[4], bh[4];
#pragma unroll
      for (int fm = 0; fm < 4; fm++) {
        int r = wr * 64 + fm * 16 + (l & 15);
        ah[fm] = *(const bf16x8*)&As[r * 64 + ks * 32 + (l >> 4) * 8];
      }
#pragma unroll
      for (int fn = 0; fn < 4; fn++) {
        int c = wc * 64 + fn * 16 + (l & 15);
        bh[fn] = *(const bf16x8*)&Bs[c * 64 + ks * 32 + (l >> 4) * 8];
      }
#pragma unroll
      for (int fm = 0; fm < 4; fm++)
#pragma unroll
        for (int fn = 0; fn < 4; fn++)
          acc[fm][fn] = __builtin_amdgcn_mfma_f32_16x16x32_bf16(ah[fm], bh[fn], acc[fm][fn], 0, 0, 0);
    }
  }
  __syncthreads();
  float bi[4], scoll[4] = {0, 0, 0, 0}, qcoll[4] = {0, 0, 0, 0};
#pragma unroll
  for (int fn = 0; fn < 4; fn++)
    bi[fn] = bias ? bias[colbase + wc * 64 + fn * 16 + (l & 15)] : 0.0f;
#pragma unroll
  for (int fm = 0; fm < 4; fm++)
#pragma unroll
    for (int r4 = 0; r4 < 4; r4++) {
      int row = rowbase + wr * 64 + fm * 16 + (l >> 4) * 4 + r4;
#pragma unroll
      for (int fn = 0; fn < 4; fn++) {
        int col = colbase + wc * 64 + fn * 16 + (l & 15);
        float v = acc[fm][fn][r4] + bi[fn];
        size_t idx = (size_t)row * N + col;
        if (Cf) Cf[idx] = v;
        if (Ch) Ch[idx] = round1(v);
        scoll[fn] += v; qcoll[fn] += v * v;
      }
    }
  if (Ssum) {
    float* scr = (float*)As;                       // 256 floats scratch
    scr[t] = 0.0f;
    __syncthreads();
#pragma unroll
    for (int fn = 0; fn < 4; fn++) {
      int cl_ = wc * 64 + fn * 16 + (l & 15);
      atomicAdd(&scr[cl_ * 2], scoll[fn]);
      atomicAdd(&scr[cl_ * 2 + 1], qcoll[fn]);
    }
    __syncthreads();
    if (t < 128) {
      atomicAdd(&Ssum[colbase + t], scr[t * 2]);
      atomicAdd(&Ssq[colbase + t], scr[t * 2 + 1]);
    }
  }
}

// in-place BN(+relu) on bf16 T1; BN1 finalize fused (reads raw stats)
__global__ void k_bnsplit(unsigned short* __restrict__ Th,
                          const float* __restrict__ Ssum, const float* __restrict__ Ssq,
                          const float* __restrict__ g, const float* __restrict__ b) {
  size_t i = (size_t)blockIdx.x * 256 + threadIdx.x;  // 4.19M threads x4 elems
  int c4 = ((int)i & 127) * 4;
  ushort4 h4 = *(ushort4*)&Th[i * 4];
  float4 ss = *(const float4*)&Ssum[c4], qq = *(const float4*)&Ssq[c4];
  float4 gg = *(const float4*)&g[c4],    bb = *(const float4*)&b[c4];
  const float invN = 1.0f / 32768.0f;
  float x, mu, var, sc, sh;
#define BNS(cmp) \
  mu = ss.cmp * invN; var = qq.cmp * invN - mu * mu; \
  sc = rsqrtf(var + 1e-5f) * gg.cmp; sh = bb.cmp - mu * sc; \
  x = bdec(h4.cmp); x = fmaf(x, sc, sh); x = x > 0 ? x : 0; \
  h4.cmp = round1(x);
  BNS(x) BNS(y) BNS(z) BNS(w)
#undef BNS
  *(ushort4*)&Th[i * 4] = h4;
}

// ---- CSR build (edge structure is layer-invariant; built once) ----
__global__ void k_count(const int* __restrict__ lei, int* __restrict__ counts) {
  int idx = blockIdx.x * 256 + threadIdx.x;
  int g = idx >> 11, e = idx & 2047;
  int d = lei[g * 4096 + 2048 + e];
  atomicAdd(&counts[g * 256 + d], 1);
}

__global__ void k_scan(const int* __restrict__ counts, int* __restrict__ rowptr,
                       int* __restrict__ pos) {
  int g = blockIdx.x, t = threadIdx.x;
  __shared__ int sc[256];
  int own = counts[g * 256 + t];
  sc[t] = own;
  __syncthreads();
  for (int off = 1; off < 256; off <<= 1) {
    int v = 0;
    if (t >= off) v = sc[t - off];
    __syncthreads();
    sc[t] += v;
    __syncthreads();
  }
  int val = g * 2048 + sc[t] - own; // exclusive
  rowptr[g * 256 + t] = val;
  pos[g * 256 + t] = val;
  if (g == B_G - 1 && t == 255) rowptr[B_G * 256] = B_G * 2048;
}

__global__ void k_fill(const int* __restrict__ lei, const int* __restrict__ ea,
                       int* __restrict__ pos, int* __restrict__ csr) {
  int idx = blockIdx.x * 256 + threadIdx.x;
  int g = idx >> 11, e = idx & 2047;
  int s = lei[g * 4096 + e];
  int d = lei[g * 4096 + 2048 + e];
  int eav = ea[g * 2048 + e];
  int slot = atomicAdd(&pos[g * 256 + d], 1);
  csr[slot] = s | (eav << 16);
}

// z = (1+eps)*(h+vn) + sum_{e->this} relu(h[src]+vn+eemb[ea]); out bf16
__global__ __launch_bounds__(256)
void k_agg(const float* __restrict__ H,
           const float* __restrict__ hsc, const float* __restrict__ hsh,
           const float* __restrict__ vn, int vns,
           const float* __restrict__ eemb,
           const int* __restrict__ rowptr, const int* __restrict__ csr,
           const float* __restrict__ geps, int l,
           unsigned short* __restrict__ Zh) {
  __shared__ float ee[16 * 256];
  for (int i = threadIdx.x; i < 4096; i += 256) ee[i] = eemb[i];
  __syncthreads();
  int lane = threadIdx.x & 63, w = threadIdx.x >> 6;
  int m = blockIdx.x * 4 + w;
  int g = m >> 8;
  int d = lane * 4;
  float eps1 = 1.0f + geps[l];
  float4 sc4 = make_float4(0, 0, 0, 0), sh4 = make_float4(0, 0, 0, 0);
  if (hsc) { sc4 = *(const float4*)&hsc[d]; sh4 = *(const float4*)&hsh[d]; }
  float4 vn4 = *(const float4*)&vn[(size_t)g * vns + d];
  int rp = rowptr[m], rp1 = rowptr[m + 1];
  float4 acc = make_float4(0, 0, 0, 0);
  int gbase = g << 8;
  for (int j = rp; j < rp1; j++) {
    int cw = csr[j];
    int src = cw & 0xFFFF, eav = cw >> 16;
    float4 h4 = *(const float4*)&H[(size_t)(gbase + src) * 256 + d];
    if (hsc) {
      h4.x = fmaf(h4.x, sc4.x, sh4.x); h4.y = fmaf(h4.y, sc4.y, sh4.y);
      h4.z = fmaf(h4.z, sc4.z, sh4.z); h4.w = fmaf(h4.w, sc4.w, sh4.w);
      h4.x = h4.x > 0 ? h4.x : 0; h4.y = h4.y > 0 ? h4.y : 0;
      h4.z = h4.z > 0 ? h4.z : 0; h4.w = h4.w > 0 ? h4.w : 0;
    }
    const float4 e4 = *(const float4*)&ee[eav * 256 + d];
    float mx = h4.x + vn4.x + e4.x; float my = h4.y + vn4.y + e4.y;
    float mz = h4.z + vn4.z + e4.z; float mw = h4.w + vn4.w + e4.w;
    acc.x += mx > 0 ? mx : 0; acc.y += my > 0 ? my : 0;
    acc.z += mz > 0 ? mz : 0; acc.w += mw > 0 ? mw : 0;
  }
  float4 hs = *(const float4*)&H[(size_t)m * 256 + d];
  if (hsc) {
    hs.x = fmaf(hs.x, sc4.x, sh4.x); hs.y = fmaf(hs.y, sc4.y, sh4.y);
    hs.z = fmaf(hs.z, sc4.z, sh4.z); hs.w = fmaf(hs.w, sc4.w, sh4.w);
    hs.x = hs.x > 0 ? hs.x : 0; hs.y = hs.y > 0 ? hs.y : 0;
    hs.z = hs.z > 0 ? hs.z : 0; hs.w = hs.w > 0 ? hs.w : 0;
  }
  float4 z4;
  z4.x = eps1 * (hs.x + vn4.x) + acc.x;
  z4.y = eps1 * (hs.y + vn4.y) + acc.y;
  z4.z = eps1 * (hs.z + vn4.z) + acc.z;
  z4.w = eps1 * (hs.w + vn4.w) + acc.w;
  ushort4 hh;
  hh.x = round1(z4.x); hh.y = round1(z4.y);
  hh.z = round1(z4.z); hh.w = round1(z4.w);
  *(ushort4*)&Zh[(size_t)m * 256 + d] = hh;
}

// contention-free partial colsums of transformed h: VNP[p][g][256], p in {0,1}
__global__ __launch_bounds__(256)
void k_vnsum(const float* __restrict__ H,
             const float* __restrict__ hsc, const float* __restrict__ hsh,
             float* __restrict__ VNP) {
  int g = blockIdx.x >> 1, p = blockIdx.x & 1, t = threadIdx.x;
  float sc = 0, sh = 0;
  if (hsc) { sc = hsc[t]; sh = hsh[t]; }
  int base = g * 256 + p * 128;
  float s0 = 0, s1 = 0, s2 = 0, s3 = 0;           // 4-deep ILP
  for (int i = 0; i < 128; i += 4) {
    float v0 = H[(size_t)(base + i + 0) * 256 + t];
    float v1 = H[(size_t)(base + i + 1) * 256 + t];
    float v2 = H[(size_t)(base + i + 2) * 256 + t];
    float v3 = H[(size_t)(base + i + 3) * 256 + t];
    if (hsc) {
      v0 = fmaf(v0, sc, sh); v0 = v0 > 0 ? v0 : 0;
      v1 = fmaf(v1, sc, sh); v1 = v1 > 0 ? v1 : 0;
      v2 = fmaf(v2, sc, sh); v2 = v2 > 0 ? v2 : 0;
      v3 = fmaf(v3, sc, sh); v3 = v3 > 0 ? v3 : 0;
    }
    s0 += v0; s1 += v1; s2 += v2; s3 += v3;
  }
  VNP[(size_t)(p * 128 + g) * 256 + t] = (s0 + s1) + (s2 + s3);
}

// vn_out = relu(relu(vt@W1+B1)@W2+B2), vt = VNP[0][g]+VNP[1][g] + 257*vn
__global__ __launch_bounds__(256)
void k_vn(const float* __restrict__ VNP,
          const float* __restrict__ vn_in, int vns,
          const float* __restrict__ W1, const float* __restrict__ B1,
          const float* __restrict__ W2, const float* __restrict__ B2,
          float* __restrict__ vn_out) {
  int g = blockIdx.x, t = threadIdx.x;
  __shared__ float vt[256];
  __shared__ float u[512];
  vt[t] = VNP[(size_t)g * 256 + t] + VNP[(size_t)(128 + g) * 256 + t]
        + 257.0f * vn_in[(size_t)g * vns + t];
  __syncthreads();
  for (int o = t; o < 512; o += 256) {
    float a = B1[o];
    for (int k = 0; k < 256; k++) a = fmaf(vt[k], W1[k * 512 + o], a);
    u[o] = a > 0 ? a : 0;
  }
  __syncthreads();
  float a = B2[t];
  for (int k = 0; k < 512; k++) a = fmaf(u[k], W2[k * 256 + t], a);
  vn_out[g * 256 + t] = a > 0 ? a : 0;
}

__global__ void k_bnfin(const float* __restrict__ Ssum, const float* __restrict__ Ssq,
                        const float* __restrict__ g, const float* __restrict__ b,
                        float* __restrict__ scale, float* __restrict__ shift,
                        int NC, float invN) {
  int c = blockIdx.x * 256 + threadIdx.x;
  if (c >= NC) return;
  float mu = Ssum[c] * invN;
  float var = Ssq[c] * invN - mu * mu;
  float rs = rsqrtf(var + 1e-5f);
  float s = rs * g[c];
  scale[c] = s;
  shift[c] = b[c] - mu * s;
}

// out = t2*sc[c]+sh[c] (final BN, JK='last', no relu)
__global__ void k_final(const float* __restrict__ T2, const float* __restrict__ sc,
                        const float* __restrict__ sh, float* __restrict__ out) {
  int i = blockIdx.x * 256 + threadIdx.x; // 2097152 float4s
  int c4 = (i & 63) * 4;
  float4 v = *(const float4*)&T2[(size_t)i * 4];
  float4 s4 = *(const float4*)&sc[c4];
  float4 h4 = *(const float4*)&sh[c4];
  v.x = fmaf(v.x, s4.x, h4.x); v.y = fmaf(v.y, s4.y, h4.y);
  v.z = fmaf(v.z, s4.z, h4.z); v.w = fmaf(v.w, s4.w, h4.w);
  *(float4*)&out[(size_t)i * 4] = v;
}

extern "C" void kernel_launch(void* const* d_in, const int* in_sizes, int n_in,
                              void* d_out, int out_size, void* d_ws, size_t ws_size,
                              hipStream_t stream) {
  (void)in_sizes; (void)n_in; (void)out_size; (void)ws_size;
  const int*   atom_idx = (const int*)d_in[0];
  const int*   lei      = (const int*)d_in[1];
  const int*   eattr    = (const int*)d_in[2];
  const float* atom_emb = (const float*)d_in[4];
  const float* bemb_h   = (const float*)d_in[5];
  const float* elw      = (const float*)d_in[6];
  const float* elb      = (const float*)d_in[7];
  const float* bemb_l   = (const float*)d_in[8];
  const float* geps     = (const float*)d_in[9];
  const float* mw1      = (const float*)d_in[10];
  const float* mb1      = (const float*)d_in[11];
  const float* mbng     = (const float*)d_in[12];
  const float* mbnb     = (const float*)d_in[13];
  const float* mw2      = (const float*)d_in[14];
  const float* mb2      = (const float*)d_in[15];
  const float* obng     = (const float*)d_in[16];
  const float* obnb     = (const float*)d_in[17];
  const float* vne      = (const float*)d_in[18];
  const float* vw1      = (const float*)d_in[19];
  const float* vb1      = (const float*)d_in[20];
  const float* vw2      = (const float*)d_in[21];
  const float* vb2      = (const float*)d_in[22];
  float* out = (float*)d_out;

  // ws layout (33.55MB units): A_, X0T, X1T, YT, Z_, tail (~6.5MB)
  float* W   = (float*)d_ws;
  float* A_  = W;
  float* X0T = W + (size_t)FBUF;
  float* X1T = W + (size_t)2 * FBUF;
  float* YT  = W + (size_t)3 * FBUF;
  float* Z_  = W + (size_t)4 * FBUF;
  float* SM  = W + (size_t)5 * FBUF;
  float* EWT = SM;                   // 16
  float* S1S = SM + 256;             // 512
  float* S1Q = SM + 768;             // 512
  float* S2S = SM + 1280;            // 256
  float* S2Q = SM + 1536;            // 256  (S1S..S2Q contiguous 1536)
  float* SC2 = SM + 1792;            // 256
  float* SH2 = SM + 2048;            // 256
  float* VNA = SM + 2304;            // 32768
  float* VNB = SM + 35072;           // 32768
  int* ROWPTR = (int*)(SM + 67840);  // 32772
  int* POS    = ROWPTR + 32772;      // 32768
  int* COUNTS = POS + 32768;         // 32768
  int* CSR    = COUNTS + 32768;      // 262144
  unsigned short* W1hT = (unsigned short*)(SM + 428544);  // 5*512*256 shorts
  unsigned short* W1lT = (unsigned short*)(SM + 756224);
  unsigned short* W2hT = (unsigned short*)(SM + 1083904); // 5*256*512 shorts
  unsigned short* W2lT = (unsigned short*)(SM + 1411584);
  float* T2 = A_;
  float* H0 = X0T;
  unsigned short* T1h = (unsigned short*)X1T;  // [32768][512] bf16 = 33.5MB
  unsigned short* Zh  = (unsigned short*)Z_;   // [32768][256] bf16 = 16.7MB
  int* PACKED = (int*)Z_;
  float* VNP  = (float*)POS;         // [2][128][256]; POS/COUNTS dead after CSR build

  // ---- stage 1: dense learned-adjacency propagation (transposed space) ----
  k_zero<<<8192, 256, 0, stream>>>((uint4*)A_, 2097152);
  k_zero<<<8192, 256, 0, stream>>>((uint4*)PACKED, 2097152);
  k_zero<<<32, 256, 0, stream>>>((uint4*)COUNTS, 8192);
  k_ewtbl<<<1, 1024, 0, stream>>>(bemb_h, elw, elb, EWT);
  k_pack_adj<<<NEDGE / 256, 256, 0, stream>>>(lei, eattr, PACKED);
  k_unpack_adj<<<32768, 256, 0, stream>>>(PACKED, EWT, A_);
  k_addeye<<<NNODE / 256, 256, 0, stream>>>(A_);
  k_degnorm<<<B_G, 256, 0, stream>>>(A_);
  // weight transpose+split (once)
  k_wtsplit<<<dim3(8, 4, 5), 256, 0, stream>>>(mw1, W1hT, W1lT, 256, 512, 131072, 131072);
  k_wtsplit<<<dim3(4, 8, 5), 256, 0, stream>>>(mw2, W2hT, W2lT, 512, 256, 131072, 131072);
  k_feaT<<<32768, 256, 0, stream>>>(atom_idx, atom_emb, X0T, YT);
  // order=3: Xt_next = Xt @ A^T (== (A@X)^T), Yt accumulates
  k_mgemm<<<dim3(2, 2, B_G), 256, 0, stream>>>(X0T, A_, X1T, YT, 256, 256, 65536, 65536, 65536);
  k_mgemm<<<dim3(2, 2, B_G), 256, 0, stream>>>(X1T, A_, X0T, YT, 256, 256, 65536, 65536, 65536);
  k_mgemm<<<dim3(2, 2, B_G), 256, 0, stream>>>(X0T, A_, X1T, YT, 256, 256, 65536, 65536, 65536);
  // H0[n][e] = 0.25 * YT[e][n]
  k_transp<<<dim3(4, 4, B_G), 256, 0, stream>>>(YT, H0, 256, 256, 65536, 65536, 0.25f);

  // ---- CSR (once; edges invariant across layers) ----
  k_count<<<NEDGE / 256, 256, 0, stream>>>(lei, COUNTS);
  k_scan<<<B_G, 256, 0, stream>>>(COUNTS, ROWPTR, POS);
  k_fill<<<NEDGE / 256, 256, 0, stream>>>(lei, eattr, POS, CSR);

  // ---- GIN + virtual-node stack ----
  const float* vn_cur = vne; int vns = 0;   // layer0 vn = vn_emb broadcast
  float* vn_next = VNA;
  for (int l = 0; l < NL; l++) {
    const float* hsrc = (l == 0) ? H0 : T2;
    const float* hsc  = (l == 0) ? nullptr : SC2;
    const float* hsh  = (l == 0) ? nullptr : SH2;
    k_agg<<<NNODE / 4, 256, 0, stream>>>(hsrc, hsc, hsh, vn_cur, vns,
        bemb_l + (size_t)l * 16 * EMB, ROWPTR, CSR, geps, l, Zh);
    if (l < NL - 1) {
      k_vnsum<<<256, 256, 0, stream>>>(hsrc, hsc, hsh, VNP);
      k_vn<<<B_G, 256, 0, stream>>>(VNP, vn_cur, vns,
          vw1 + (size_t)l * EMB * 512, vb1 + (size_t)l * 512,
          vw2 + (size_t)l * 512 * EMB, vb2 + (size_t)l * EMB, vn_next);
    }
    k_zero<<<2, 256, 0, stream>>>((uint4*)S1S, 384);   // S1S,S1Q,S2S,S2Q
    k_bgemm<<<dim3(4, 256), 256, 0, stream>>>(Zh,
        W1hT + (size_t)l * 131072, mb1 + (size_t)l * 512,
        nullptr, T1h, S1S, S1Q, 256, 512);
    k_bnsplit<<<16384, 256, 0, stream>>>(T1h, S1S, S1Q,
        mbng + (size_t)l * 512, mbnb + (size_t)l * 512);
    k_bgemm<<<dim3(2, 256), 256, 0, stream>>>(T1h,
        W2hT + (size_t)l * 131072, mb2 + (size_t)l * 256,
        T2, nullptr, S2S, S2Q, 512, 256);
    k_bnfin<<<1, 256, 0, stream>>>(S2S, S2Q, obng + (size_t)l * EMB,
        obnb + (size_t)l * EMB, SC2, SH2, 256, 1.0f / NNODE);
    if (l < NL - 1) {
      vn_cur = vn_next; vns = EMB;
      vn_next = (vn_next == VNA) ? VNB : VNA;
    }
  }
  k_final<<<8192, 256, 0, stream>>>(T2, SC2, SH2, out);
}

// Round 9
// 1083.752 us; speedup vs baseline: 2.7434x; 1.1048x over previous
//
#include <hip/hip_runtime.h>
#include <math.h>

// GNN_node_Virtualnode: B=128 graphs, 256 nodes/graph, 2048 edges/graph,
// emb=256, 5 GIN layers + virtual node, learned dense-adjacency propagation.
// Round 9: prop converted to pure bf16 via the batched k_bgemm (A pre-scaled
// to bf16 once); Y-accumulate RMW replaced by separate X buffers + fused
// sum-transpose. Prologue trimmed (no A pre-zero, eye folded into unpack,
// degnorm = sums-only + scale fused into A-round). MLP path as R8 (bf16).

#define B_G   128
#define NPG   256
#define EPG   2048
#define EMB   256
#define NL    5
#define NNODE (B_G*NPG)   // 32768
#define NEDGE (B_G*EPG)   // 262144
#define FBUF  8388608     // floats per 33.55MB buffer

typedef __attribute__((ext_vector_type(8))) short bf16x8;
typedef __attribute__((ext_vector_type(4))) float f32x4;

// ---------------- helpers ----------------
__device__ __forceinline__ unsigned short round1(float x) {
  // round-to-nearest-even bf16
  unsigned u = __builtin_bit_cast(unsigned, x);
  return (unsigned short)((u + 0x7FFFu + ((u >> 16) & 1u)) >> 16);
}

__device__ __forceinline__ float bdec(unsigned short h) {
  return __builtin_bit_cast(float, (unsigned)h << 16);
}

__device__ __forceinline__ void gload16(unsigned short* lds, const unsigned short* g) {
  // async global->LDS, 16B/lane; LDS dest = wave-uniform base + lane*16
  __builtin_amdgcn_global_load_lds(
      (const __attribute__((address_space(1))) unsigned int*)g,
      (__attribute__((address_space(3))) unsigned int*)lds, 16, 0, 0);
}

__global__ void k_zero(uint4* p, int n16) {
  int i = blockIdx.x * 256 + threadIdx.x;
  if (i < n16) p[i] = make_uint4(0, 0, 0, 0);
}

// 16-entry sigmoid edge-weight table: 16 waves, one per bond value
__global__ void k_ewtbl(const float* __restrict__ bh, const float* __restrict__ w,
                        const float* __restrict__ b, float* __restrict__ tbl) {
  int v = threadIdx.x >> 6, t = threadIdx.x & 63;
  float p = bh[v * 64 + t] * w[t];
  for (int off = 32; off; off >>= 1) p += __shfl_down(p, off, 64);
  if (t == 0) tbl[v] = 1.0f / (1.0f + expf(-(p + b[0])));
}

// Deterministic duplicate resolution: last edge (max e) wins.
__global__ void k_pack_adj(const int* __restrict__ lei, const int* __restrict__ ea,
                           int* __restrict__ packed) {
  int idx = blockIdx.x * 256 + threadIdx.x;       // NEDGE
  int g = idx >> 11, e = idx & 2047;
  int s = lei[g * 4096 + e];
  int d = lei[g * 4096 + 2048 + e];
  int v = ((e + 1) << 4) | ea[g * 2048 + e];
  atomicMax(&packed[g * 65536 + s * 256 + d], v);
}

// unpack + eye folded; writes EVERY element (no pre-zero of adj needed)
__global__ void k_unpack_adj(const int* __restrict__ packed,
                             const float* __restrict__ tbl, float* __restrict__ adj) {
  int idx = blockIdx.x * 256 + threadIdx.x;       // 8388608
  int v = packed[idx];
  int r = (idx >> 8) & 255, c = idx & 255;
  adj[idx] = (v ? tbl[v & 15] : 0.0f) + (r == c ? 1.0f : 0.0f);
}

// per-graph colsum^-1/2 and rowsum^-1/2 (sums only; scaling fused into k_ascale)
__global__ __launch_bounds__(256)
void k_degsums(const float* __restrict__ adj, float* __restrict__ CSv,
               float* __restrict__ RCv) {
  int g = blockIdx.x, t = threadIdx.x;
  const float* Ag = adj + (size_t)g * 65536;
  float s0 = 0, s1 = 0, s2 = 0, s3 = 0;
  for (int i = 0; i < 256; i += 4) {              // colsum(t), coalesced
    s0 += Ag[(i + 0) * 256 + t]; s1 += Ag[(i + 1) * 256 + t];
    s2 += Ag[(i + 2) * 256 + t]; s3 += Ag[(i + 3) * 256 + t];
  }
  CSv[g * 256 + t] = rsqrtf((s0 + s1) + (s2 + s3));
  float4 r0 = make_float4(0, 0, 0, 0), r1 = r0, r2 = r0, r3 = r0;
  const float4* A4 = (const float4*)(Ag + t * 256);
  for (int j = 0; j < 64; j += 4) {               // rowsum(t)
    float4 v0 = A4[j], v1 = A4[j + 1], v2 = A4[j + 2], v3 = A4[j + 3];
    r0.x += v0.x + v0.y; r0.y += v0.z + v0.w;
    r1.x += v1.x + v1.y; r1.y += v1.z + v1.w;
    r2.x += v2.x + v2.y; r2.y += v2.z + v2.w;
    r3.x += v3.x + v3.y; r3.y += v3.z + v3.w;
  }
  RCv[g * 256 + t] = rsqrtf((r0.x + r0.y) + (r1.x + r1.y) + (r2.x + r2.y) + (r3.x + r3.y));
}

// Ahb[g][i][j] = bf16( cs[i] * adj[i][j] * rc[j] )
__global__ void k_ascale(const float* __restrict__ adj, const float* __restrict__ CSv,
                         const float* __restrict__ RCv, unsigned short* __restrict__ Ahb) {
  int flat = blockIdx.x * 256 + threadIdx.x;      // 2097152 quads
  int g = flat >> 14;
  int i = (flat >> 6) & 255, j4 = (flat & 63) * 4;
  size_t base = (size_t)g * 65536 + i * 256 + j4;
  float4 a = *(const float4*)&adj[base];
  float cs = CSv[g * 256 + i];
  float4 rc = *(const float4*)&RCv[g * 256 + j4];
  ushort4 o;
  o.x = round1(cs * a.x * rc.x); o.y = round1(cs * a.y * rc.y);
  o.z = round1(cs * a.z * rc.z); o.w = round1(cs * a.w * rc.w);
  *(ushort4*)&Ahb[base] = o;
}

// transposed bf16 fea gather: X0h[g][e][n] = bf16(atom_emb[aidx[g*256+n]][e])
__global__ void k_feaTb(const int* __restrict__ aidx, const float* __restrict__ aemb,
                        unsigned short* __restrict__ X0h) {
  int flat = blockIdx.x * 256 + threadIdx.x;      // 2097152 quads
  int base = flat * 4;
  int g = base >> 16, e = (base >> 8) & 255, n0 = base & 255;
  const int* ai = &aidx[g * 256 + n0];
  ushort4 o;
  o.x = round1(aemb[ai[0] * 256 + e]);
  o.y = round1(aemb[ai[1] * 256 + e]);
  o.z = round1(aemb[ai[2] * 256 + e]);
  o.w = round1(aemb[ai[3] * 256 + e]);
  *(ushort4*)&X0h[base] = o;
}

// fused Y-sum + transpose: H0[z][n][k] = 0.25*(X0+X1+X2+X3)[z][k][n], bf16->f32
__global__ __launch_bounds__(256)
void k_sumT(const unsigned short* __restrict__ X0, const unsigned short* __restrict__ X1,
            const unsigned short* __restrict__ X2, const unsigned short* __restrict__ X3,
            float* __restrict__ dst) {
  __shared__ float tl[64][65];
  size_t zo = (size_t)blockIdx.z * 65536;
  int n0 = blockIdx.x * 64, k0 = blockIdx.y * 64;
  int t = threadIdx.x;
  int c = (t & 15) * 4, r = t >> 4;
#pragma unroll
  for (int p = 0; p < 4; p++) {
    int rr = r + p * 16;
    size_t off = zo + (size_t)(k0 + rr) * 256 + n0 + c;
    ushort4 a = *(const ushort4*)&X0[off];
    ushort4 b = *(const ushort4*)&X1[off];
    ushort4 cc = *(const ushort4*)&X2[off];
    ushort4 d = *(const ushort4*)&X3[off];
    tl[rr][c + 0] = bdec(a.x) + bdec(b.x) + bdec(cc.x) + bdec(d.x);
    tl[rr][c + 1] = bdec(a.y) + bdec(b.y) + bdec(cc.y) + bdec(d.y);
    tl[rr][c + 2] = bdec(a.z) + bdec(b.z) + bdec(cc.z) + bdec(d.z);
    tl[rr][c + 3] = bdec(a.w) + bdec(b.w) + bdec(cc.w) + bdec(d.w);
  }
  __syncthreads();
#pragma unroll
  for (int p = 0; p < 4; p++) {
    int rr = r + p * 16;
    float4 o;
    o.x = tl[c][rr] * 0.25f;     o.y = tl[c + 1][rr] * 0.25f;
    o.z = tl[c + 2][rr] * 0.25f; o.w = tl[c + 3][rr] * 0.25f;
    *(float4*)&dst[zo + (size_t)(n0 + rr) * 256 + k0 + c] = o;
  }
}

// weight transpose + bf16 round: dh[z][N][K] = bf16(src[z][K][N])
__global__ __launch_bounds__(256)
void k_wtb(const float* __restrict__ src, unsigned short* __restrict__ dh,
           int K, int N, long ss, long sd) {
  __shared__ float tl[64][65];
  src += (size_t)blockIdx.z * ss;
  dh += (size_t)blockIdx.z * sd;
  int n0 = blockIdx.x * 64, k0 = blockIdx.y * 64;
  int t = threadIdx.x;
  int c = (t & 15) * 4, r = t >> 4;
#pragma unroll
  for (int p = 0; p < 4; p++) {
    int rr = r + p * 16;
    float4 v = *(const float4*)&src[(size_t)(k0 + rr) * N + n0 + c];
    tl[rr][c] = v.x; tl[rr][c + 1] = v.y; tl[rr][c + 2] = v.z; tl[rr][c + 3] = v.w;
  }
  __syncthreads();
#pragma unroll
  for (int p = 0; p < 4; p++) {
    int rr = r + p * 16;
    ushort4 hh;
    hh.x = round1(tl[c][rr]);     hh.y = round1(tl[c + 1][rr]);
    hh.z = round1(tl[c + 2][rr]); hh.w = round1(tl[c + 3][rr]);
    *(ushort4*)&dh[(size_t)(n0 + rr) * K + k0 + c] = hh;
  }
}

// ---- bf16 GEMM (batched): C[z] = A[z] @ B[z]^T + bias; A[M][K], B[N][K] bf16.
// 32KB LDS, global_load_lds staging. Optional fused column sum/sumsq.
// Output: fp32 Cf OR bf16 Ch.
__global__ __launch_bounds__(256, 4)
void k_bgemm(const unsigned short* __restrict__ A_g, const unsigned short* __restrict__ B_g,
             const float* __restrict__ bias, float* __restrict__ Cf,
             unsigned short* __restrict__ Ch,
             float* __restrict__ Ssum, float* __restrict__ Ssq, int K, int N,
             long zA, long zB, long zC) {
  __shared__ alignas(16) unsigned short As[128 * 64];
  __shared__ alignas(16) unsigned short Bs[128 * 64];
  int z = blockIdx.z;
  A_g += (size_t)z * zA; B_g += (size_t)z * zB;
  if (Cf) Cf += (size_t)z * zC;
  if (Ch) Ch += (size_t)z * zC;
  int rowbase = blockIdx.y * 128, colbase = blockIdx.x * 128;
  int t = threadIdx.x, l = t & 63, wid = t >> 6;
  int wr = wid >> 1, wc = wid & 1;
  int r8 = l >> 3, cb = (l & 7) * 8;               // staging lane -> (row, col)
  f32x4 acc[4][4];
#pragma unroll
  for (int i = 0; i < 4; i++)
#pragma unroll
    for (int j = 0; j < 4; j++) acc[i][j] = (f32x4){0, 0, 0, 0};

  for (int k0 = 0; k0 < K; k0 += 64) {
    __syncthreads();                               // prior readers done
#pragma unroll
    for (int i = 0; i < 4; i++) {
      int chunk = wid * 4 + i;                     // 0..15 -> 8 rows each
      int row = chunk * 8 + r8;
      gload16(As + chunk * 512, A_g + (size_t)(rowbase + row) * K + k0 + cb);
      gload16(Bs + chunk * 512, B_g + (size_t)(colbase + row) * K + k0 + cb);
    }
    __syncthreads();                               // vmcnt(0) drain + barrier
#pragma unroll
    for (int ks = 0; ks < 2; ks++) {
      bf16x8 ah[4], bh[4];
#pragma unroll
      for (int fm = 0; fm < 4; fm++) {
        int r = wr * 64 + fm * 16 + (l & 15);
        ah[fm] = *(const bf16x8*)&As[r * 64 + ks * 32 + (l >> 4) * 8];
      }
#pragma unroll
      for (int fn = 0; fn < 4; fn++) {
        int c = wc * 64 + fn * 16 + (l & 15);
        bh[fn] = *(const bf16x8*)&Bs[c * 64 + ks * 32 + (l >> 4) * 8];
      }
#pragma unroll
      for (int fm = 0; fm < 4; fm++)
#pragma unroll
        for (int fn = 0; fn < 4; fn++)
          acc[fm][fn] = __builtin_amdgcn_mfma_f32_16x16x32_bf16(ah[fm], bh[fn], acc[fm][fn], 0, 0, 0);
    }
  }
  __syncthreads();
  float bi[4], scoll[4] = {0, 0, 0, 0}, qcoll[4] = {0, 0, 0, 0};
#pragma unroll
  for (int fn = 0; fn < 4; fn++)
    bi[fn] = bias ? bias[colbase + wc * 64 + fn * 16 + (l & 15)] : 0.0f;
#pragma unroll
  for (int fm = 0; fm < 4; fm++)
#pragma unroll
    for (int r4 = 0; r4 < 4; r4++) {
      int row = rowbase + wr * 64 + fm * 16 + (l >> 4) * 4 + r4;
#pragma unroll
      for (int fn = 0; fn < 4; fn++) {
        int col = colbase + wc * 64 + fn * 16 + (l & 15);
        float v = acc[fm][fn][r4] + bi[fn];
        size_t idx = (size_t)row * N + col;
        if (Cf) Cf[idx] = v;
        if (Ch) Ch[idx] = round1(v);
        scoll[fn] += v; qcoll[fn] += v * v;
      }
    }
  if (Ssum) {
    float* scr = (float*)As;                       // 256 floats scratch
    scr[t] = 0.0f;
    __syncthreads();
#pragma unroll
    for (int fn = 0; fn < 4; fn++) {
      int cl_ = wc * 64 + fn * 16 + (l & 15);
      atomicAdd(&scr[cl_ * 2], scoll[fn]);
      atomicAdd(&scr[cl_ * 2 + 1], qcoll[fn]);
    }
    __syncthreads();
    if (t < 128) {
      atomicAdd(&Ssum[colbase + t], scr[t * 2]);
      atomicAdd(&Ssq[colbase + t], scr[t * 2 + 1]);
    }
  }
}

// in-place BN(+relu) on bf16 T1; BN1 finalize fused (reads raw stats)
__global__ void k_bnsplit(unsigned short* __restrict__ Th,
                          const float* __restrict__ Ssum, const float* __restrict__ Ssq,
                          const float* __restrict__ g, const float* __restrict__ b) {
  size_t i = (size_t)blockIdx.x * 256 + threadIdx.x;  // 4.19M threads x4 elems
  int c4 = ((int)i & 127) * 4;
  ushort4 h4 = *(ushort4*)&Th[i * 4];
  float4 ss = *(const float4*)&Ssum[c4], qq = *(const float4*)&Ssq[c4];
  float4 gg = *(const float4*)&g[c4],    bb = *(const float4*)&b[c4];
  const float invN = 1.0f / 32768.0f;
  float x, mu, var, sc, sh;
#define BNS(cmp) \
  mu = ss.cmp * invN; var = qq.cmp * invN - mu * mu; \
  sc = rsqrtf(var + 1e-5f) * gg.cmp; sh = bb.cmp - mu * sc; \
  x = bdec(h4.cmp); x = fmaf(x, sc, sh); x = x > 0 ? x : 0; \
  h4.cmp = round1(x);
  BNS(x) BNS(y) BNS(z) BNS(w)
#undef BNS
  *(ushort4*)&Th[i * 4] = h4;
}

// ---- CSR build (edge structure is layer-invariant; built once) ----
__global__ void k_count(const int* __restrict__ lei, int* __restrict__ counts) {
  int idx = blockIdx.x * 256 + threadIdx.x;
  int g = idx >> 11, e = idx & 2047;
  int d = lei[g * 4096 + 2048 + e];
  atomicAdd(&counts[g * 256 + d], 1);
}

__global__ void k_scan(const int* __restrict__ counts, int* __restrict__ rowptr,
                       int* __restrict__ pos) {
  int g = blockIdx.x, t = threadIdx.x;
  __shared__ int sc[256];
  int own = counts[g * 256 + t];
  sc[t] = own;
  __syncthreads();
  for (int off = 1; off < 256; off <<= 1) {
    int v = 0;
    if (t >= off) v = sc[t - off];
    __syncthreads();
    sc[t] += v;
    __syncthreads();
  }
  int val = g * 2048 + sc[t] - own; // exclusive
  rowptr[g * 256 + t] = val;
  pos[g * 256 + t] = val;
  if (g == B_G - 1 && t == 255) rowptr[B_G * 256] = B_G * 2048;
}

__global__ void k_fill(const int* __restrict__ lei, const int* __restrict__ ea,
                       int* __restrict__ pos, int* __restrict__ csr) {
  int idx = blockIdx.x * 256 + threadIdx.x;
  int g = idx >> 11, e = idx & 2047;
  int s = lei[g * 4096 + e];
  int d = lei[g * 4096 + 2048 + e];
  int eav = ea[g * 2048 + e];
  int slot = atomicAdd(&pos[g * 256 + d], 1);
  csr[slot] = s | (eav << 16);
}

// z = (1+eps)*(h+vn) + sum_{e->this} relu(h[src]+vn+eemb[ea]); out bf16
__global__ __launch_bounds__(256)
void k_agg(const float* __restrict__ H,
           const float* __restrict__ hsc, const float* __restrict__ hsh,
           const float* __restrict__ vn, int vns,
           const float* __restrict__ eemb,
           const int* __restrict__ rowptr, const int* __restrict__ csr,
           const float* __restrict__ geps, int l,
           unsigned short* __restrict__ Zh) {
  __shared__ float ee[16 * 256];
  for (int i = threadIdx.x; i < 4096; i += 256) ee[i] = eemb[i];
  __syncthreads();
  int lane = threadIdx.x & 63, w = threadIdx.x >> 6;
  int m = blockIdx.x * 4 + w;
  int g = m >> 8;
  int d = lane * 4;
  float eps1 = 1.0f + geps[l];
  float4 sc4 = make_float4(0, 0, 0, 0), sh4 = make_float4(0, 0, 0, 0);
  if (hsc) { sc4 = *(const float4*)&hsc[d]; sh4 = *(const float4*)&hsh[d]; }
  float4 vn4 = *(const float4*)&vn[(size_t)g * vns + d];
  int rp = rowptr[m], rp1 = rowptr[m + 1];
  float4 acc = make_float4(0, 0, 0, 0);
  int gbase = g << 8;
  for (int j = rp; j < rp1; j++) {
    int cw = csr[j];
    int src = cw & 0xFFFF, eav = cw >> 16;
    float4 h4 = *(const float4*)&H[(size_t)(gbase + src) * 256 + d];
    if (hsc) {
      h4.x = fmaf(h4.x, sc4.x, sh4.x); h4.y = fmaf(h4.y, sc4.y, sh4.y);
      h4.z = fmaf(h4.z, sc4.z, sh4.z); h4.w = fmaf(h4.w, sc4.w, sh4.w);
      h4.x = h4.x > 0 ? h4.x : 0; h4.y = h4.y > 0 ? h4.y : 0;
      h4.z = h4.z > 0 ? h4.z : 0; h4.w = h4.w > 0 ? h4.w : 0;
    }
    const float4 e4 = *(const float4*)&ee[eav * 256 + d];
    float mx = h4.x + vn4.x + e4.x; float my = h4.y + vn4.y + e4.y;
    float mz = h4.z + vn4.z + e4.z; float mw = h4.w + vn4.w + e4.w;
    acc.x += mx > 0 ? mx : 0; acc.y += my > 0 ? my : 0;
    acc.z += mz > 0 ? mz : 0; acc.w += mw > 0 ? mw : 0;
  }
  float4 hs = *(const float4*)&H[(size_t)m * 256 + d];
  if (hsc) {
    hs.x = fmaf(hs.x, sc4.x, sh4.x); hs.y = fmaf(hs.y, sc4.y, sh4.y);
    hs.z = fmaf(hs.z, sc4.z, sh4.z); hs.w = fmaf(hs.w, sc4.w, sh4.w);
    hs.x = hs.x > 0 ? hs.x : 0; hs.y = hs.y > 0 ? hs.y : 0;
    hs.z = hs.z > 0 ? hs.z : 0; hs.w = hs.w > 0 ? hs.w : 0;
  }
  float4 z4;
  z4.x = eps1 * (hs.x + vn4.x) + acc.x;
  z4.y = eps1 * (hs.y + vn4.y) + acc.y;
  z4.z = eps1 * (hs.z + vn4.z) + acc.z;
  z4.w = eps1 * (hs.w + vn4.w) + acc.w;
  ushort4 hh;
  hh.x = round1(z4.x); hh.y = round1(z4.y);
  hh.z = round1(z4.z); hh.w = round1(z4.w);
  *(ushort4*)&Zh[(size_t)m * 256 + d] = hh;
}

// contention-free partial colsums of transformed h: VNP[p][g][256], p in {0,1}
__global__ __launch_bounds__(256)
void k_vnsum(const float* __restrict__ H,
             const float* __restrict__ hsc, const float* __restrict__ hsh,
             float* __restrict__ VNP) {
  int g = blockIdx.x >> 1, p = blockIdx.x & 1, t = threadIdx.x;
  float sc = 0, sh = 0;
  if (hsc) { sc = hsc[t]; sh = hsh[t]; }
  int base = g * 256 + p * 128;
  float s0 = 0, s1 = 0, s2 = 0, s3 = 0;           // 4-deep ILP
  for (int i = 0; i < 128; i += 4) {
    float v0 = H[(size_t)(base + i + 0) * 256 + t];
    float v1 = H[(size_t)(base + i + 1) * 256 + t];
    float v2 = H[(size_t)(base + i + 2) * 256 + t];
    float v3 = H[(size_t)(base + i + 3) * 256 + t];
    if (hsc) {
      v0 = fmaf(v0, sc, sh); v0 = v0 > 0 ? v0 : 0;
      v1 = fmaf(v1, sc, sh); v1 = v1 > 0 ? v1 : 0;
      v2 = fmaf(v2, sc, sh); v2 = v2 > 0 ? v2 : 0;
      v3 = fmaf(v3, sc, sh); v3 = v3 > 0 ? v3 : 0;
    }
    s0 += v0; s1 += v1; s2 += v2; s3 += v3;
  }
  VNP[(size_t)(p * 128 + g) * 256 + t] = (s0 + s1) + (s2 + s3);
}

// vn_out = relu(relu(vt@W1+B1)@W2+B2), vt = VNP[0][g]+VNP[1][g] + 257*vn
__global__ __launch_bounds__(256)
void k_vn(const float* __restrict__ VNP,
          const float* __restrict__ vn_in, int vns,
          const float* __restrict__ W1, const float* __restrict__ B1,
          const float* __restrict__ W2, const float* __restrict__ B2,
          float* __restrict__ vn_out) {
  int g = blockIdx.x, t = threadIdx.x;
  __shared__ float vt[256];
  __shared__ float u[512];
  vt[t] = VNP[(size_t)g * 256 + t] + VNP[(size_t)(128 + g) * 256 + t]
        + 257.0f * vn_in[(size_t)g * vns + t];
  __syncthreads();
  for (int o = t; o < 512; o += 256) {
    float a = B1[o];
    for (int k = 0; k < 256; k++) a = fmaf(vt[k], W1[k * 512 + o], a);
    u[o] = a > 0 ? a : 0;
  }
  __syncthreads();
  float a = B2[t];
  for (int k = 0; k < 512; k++) a = fmaf(u[k], W2[k * 256 + t], a);
  vn_out[g * 256 + t] = a > 0 ? a : 0;
}

__global__ void k_bnfin(const float* __restrict__ Ssum, const float* __restrict__ Ssq,
                        const float* __restrict__ g, const float* __restrict__ b,
                        float* __restrict__ scale, float* __restrict__ shift,
                        int NC, float invN) {
  int c = blockIdx.x * 256 + threadIdx.x;
  if (c >= NC) return;
  float mu = Ssum[c] * invN;
  float var = Ssq[c] * invN - mu * mu;
  float rs = rsqrtf(var + 1e-5f);
  float s = rs * g[c];
  scale[c] = s;
  shift[c] = b[c] - mu * s;
}

// out = t2*sc[c]+sh[c] (final BN, JK='last', no relu)
__global__ void k_final(const float* __restrict__ T2, const float* __restrict__ sc,
                        const float* __restrict__ sh, float* __restrict__ out) {
  int i = blockIdx.x * 256 + threadIdx.x; // 2097152 float4s
  int c4 = (i & 63) * 4;
  float4 v = *(const float4*)&T2[(size_t)i * 4];
  float4 s4 = *(const float4*)&sc[c4];
  float4 h4 = *(const float4*)&sh[c4];
  v.x = fmaf(v.x, s4.x, h4.x); v.y = fmaf(v.y, s4.y, h4.y);
  v.z = fmaf(v.z, s4.z, h4.z); v.w = fmaf(v.w, s4.w, h4.w);
  *(float4*)&out[(size_t)i * 4] = v;
}

extern "C" void kernel_launch(void* const* d_in, const int* in_sizes, int n_in,
                              void* d_out, int out_size, void* d_ws, size_t ws_size,
                              hipStream_t stream) {
  (void)in_sizes; (void)n_in; (void)out_size; (void)ws_size;
  const int*   atom_idx = (const int*)d_in[0];
  const int*   lei      = (const int*)d_in[1];
  const int*   eattr    = (const int*)d_in[2];
  const float* atom_emb = (const float*)d_in[4];
  const float* bemb_h   = (const float*)d_in[5];
  const float* elw      = (const float*)d_in[6];
  const float* elb      = (const float*)d_in[7];
  const float* bemb_l   = (const float*)d_in[8];
  const float* geps     = (const float*)d_in[9];
  const float* mw1      = (const float*)d_in[10];
  const float* mb1      = (const float*)d_in[11];
  const float* mbng     = (const float*)d_in[12];
  const float* mbnb     = (const float*)d_in[13];
  const float* mw2      = (const float*)d_in[14];
  const float* mb2      = (const float*)d_in[15];
  const float* obng     = (const float*)d_in[16];
  const float* obnb     = (const float*)d_in[17];
  const float* vne      = (const float*)d_in[18];
  const float* vw1      = (const float*)d_in[19];
  const float* vb1      = (const float*)d_in[20];
  const float* vw2      = (const float*)d_in[21];
  const float* vb2      = (const float*)d_in[22];
  float* out = (float*)d_out;

  // ws layout (33.55MB units):
  // U0: adj fp32 -> later T2 fp32
  // U1: X0h|X1h bf16 -> later T1h bf16 (full unit)
  // U2: X2h|X3h bf16
  // U3: PACKED int -> later H0 fp32
  // U4: Zh bf16 | Ahb bf16
  // tail: tables, stats, CSR, weights
  float* W   = (float*)d_ws;
  float* A_  = W;
  float* U1  = W + (size_t)FBUF;
  float* U2  = W + (size_t)2 * FBUF;
  float* U3  = W + (size_t)3 * FBUF;
  float* Z_  = W + (size_t)4 * FBUF;
  float* SM  = W + (size_t)5 * FBUF;
  float* EWT = SM;                   // 16
  float* S1S = SM + 256;             // 512
  float* S1Q = SM + 768;             // 512
  float* S2S = SM + 1280;            // 256
  float* S2Q = SM + 1536;            // 256  (S1S..S2Q contiguous 1536)
  float* SC2 = SM + 1792;            // 256
  float* SH2 = SM + 2048;            // 256
  float* VNA = SM + 2304;            // 32768
  float* VNB = SM + 35072;           // 32768
  float* CSv = SM + 67840;           // 32768
  float* RCv = SM + 100608;          // 32768
  int* ROWPTR = (int*)(SM + 133376); // 32772
  int* POS    = ROWPTR + 32772;      // 32768
  int* COUNTS = POS + 32768;         // 32768
  int* CSR    = COUNTS + 32768;      // 262144
  unsigned short* W1hT = (unsigned short*)(SM + 493952);  // 5*512*256 shorts
  unsigned short* W2hT = (unsigned short*)(SM + 821632);  // 5*256*512 shorts
  float* T2 = A_;
  float* H0 = U3;
  int* PACKED = (int*)U3;
  unsigned short* X0h = (unsigned short*)U1;
  unsigned short* X1h = X0h + 8388608;
  unsigned short* X2h = (unsigned short*)U2;
  unsigned short* X3h = X2h + 8388608;
  unsigned short* T1h = (unsigned short*)U1;   // [32768][512] bf16 = full U1
  unsigned short* Zh  = (unsigned short*)Z_;   // [32768][256] bf16, U4 lo half
  unsigned short* Ahb = (unsigned short*)(Z_ + (size_t)FBUF / 2); // U4 hi half
  float* VNP  = (float*)POS;         // [2][128][256]; POS dead after CSR build

  // ---- stage 1: dense learned-adjacency propagation (bf16, transposed) ----
  k_zero<<<8192, 256, 0, stream>>>((uint4*)PACKED, 2097152);
  k_zero<<<32, 256, 0, stream>>>((uint4*)COUNTS, 8192);
  k_ewtbl<<<1, 1024, 0, stream>>>(bemb_h, elw, elb, EWT);
  k_pack_adj<<<NEDGE / 256, 256, 0, stream>>>(lei, eattr, PACKED);
  k_unpack_adj<<<32768, 256, 0, stream>>>(PACKED, EWT, A_);   // + eye
  k_degsums<<<B_G, 256, 0, stream>>>(A_, CSv, RCv);
  k_ascale<<<8192, 256, 0, stream>>>(A_, CSv, RCv, Ahb);
  // weight transpose + bf16 round (once)
  k_wtb<<<dim3(8, 4, 5), 256, 0, stream>>>(mw1, W1hT, 256, 512, 131072, 131072);
  k_wtb<<<dim3(4, 8, 5), 256, 0, stream>>>(mw2, W2hT, 512, 256, 131072, 131072);
  k_feaTb<<<8192, 256, 0, stream>>>(atom_idx, atom_emb, X0h);
  // order=3: Xt_{i+1} = Xt_i @ A^T (batched bf16 MFMA GEMM, no Y RMW)
  k_bgemm<<<dim3(2, 2, B_G), 256, 0, stream>>>(X0h, Ahb, nullptr, nullptr, X1h,
      nullptr, nullptr, 256, 256, 65536, 65536, 65536);
  k_bgemm<<<dim3(2, 2, B_G), 256, 0, stream>>>(X1h, Ahb, nullptr, nullptr, X2h,
      nullptr, nullptr, 256, 256, 65536, 65536, 65536);
  k_bgemm<<<dim3(2, 2, B_G), 256, 0, stream>>>(X2h, Ahb, nullptr, nullptr, X3h,
      nullptr, nullptr, 256, 256, 65536, 65536, 65536);
  // H0[n][e] = 0.25*(X0+X1+X2+X3)[e][n]  (PACKED dead; H0 = U3)
  k_sumT<<<dim3(4, 4, B_G), 256, 0, stream>>>(X0h, X1h, X2h, X3h, H0);

  // ---- CSR (once; edges invariant across layers) ----
  k_count<<<NEDGE / 256, 256, 0, stream>>>(lei, COUNTS);
  k_scan<<<B_G, 256, 0, stream>>>(COUNTS, ROWPTR, POS);
  k_fill<<<NEDGE / 256, 256, 0, stream>>>(lei, eattr, POS, CSR);

  // ---- GIN + virtual-node stack ----
  const float* vn_cur = vne; int vns = 0;   // layer0 vn = vn_emb broadcast
  float* vn_next = VNA;
  for (int l = 0; l < NL; l++) {
    const float* hsrc = (l == 0) ? H0 : T2;
    const float* hsc  = (l == 0) ? nullptr : SC2;
    const float* hsh  = (l == 0) ? nullptr : SH2;
    k_agg<<<NNODE / 4, 256, 0, stream>>>(hsrc, hsc, hsh, vn_cur, vns,
        bemb_l + (size_t)l * 16 * EMB, ROWPTR, CSR, geps, l, Zh);
    if (l < NL - 1) {
      k_vnsum<<<256, 256, 0, stream>>>(hsrc, hsc, hsh, VNP);
      k_vn<<<B_G, 256, 0, stream>>>(VNP, vn_cur, vns,
          vw1 + (size_t)l * EMB * 512, vb1 + (size_t)l * 512,
          vw2 + (size_t)l * 512 * EMB, vb2 + (size_t)l * EMB, vn_next);
    }
    k_zero<<<2, 256, 0, stream>>>((uint4*)S1S, 384);   // S1S,S1Q,S2S,S2Q
    k_bgemm<<<dim3(4, 256, 1), 256, 0, stream>>>(Zh,
        W1hT + (size_t)l * 131072, mb1 + (size_t)l * 512,
        nullptr, T1h, S1S, S1Q, 256, 512, 0, 0, 0);
    k_bnsplit<<<16384, 256, 0, stream>>>(T1h, S1S, S1Q,
        mbng + (size_t)l * 512, mbnb + (size_t)l * 512);
    k_bgemm<<<dim3(2, 256, 1), 256, 0, stream>>>(T1h,
        W2hT + (size_t)l * 131072, mb2 + (size_t)l * 256,
        T2, nullptr, S2S, S2Q, 512, 256, 0, 0, 0);
    k_bnfin<<<1, 256, 0, stream>>>(S2S, S2Q, obng + (size_t)l * EMB,
        obnb + (size_t)l * EMB, SC2, SH2, 256, 1.0f / NNODE);
    if (l < NL - 1) {
      vn_cur = vn_next; vns = EMB;
      vn_next = (vn_next == VNA) ? VNB : VNA;
    }
  }
  k_final<<<8192, 256, 0, stream>>>(T2, SC2, SH2, out);
}

// Round 10
// 1027.774 us; speedup vs baseline: 2.8929x; 1.0545x over previous
//
#include <hip/hip_runtime.h>
#include <math.h>

// GNN_node_Virtualnode: B=128 graphs, 256 nodes/graph, 2048 edges/graph,
// emb=256, 5 GIN layers + virtual node, learned dense-adjacency propagation.
// Round 10: k_agg traffic attack — H held in bf16 for layers 0..4 inputs
// (T2b written by GEMM2 of layers 0..3; H0 bf16 from sumT), final layer T2
// stays fp32 for the output path. XCD-aware block swizzle on k_agg (no
// atomics — R5's regression was the atomics, not the swizzle).

#define B_G   128
#define NPG   256
#define EPG   2048
#define EMB   256
#define NL    5
#define NNODE (B_G*NPG)   // 32768
#define NEDGE (B_G*EPG)   // 262144
#define FBUF  8388608     // floats per 33.55MB buffer

typedef __attribute__((ext_vector_type(8))) short bf16x8;
typedef __attribute__((ext_vector_type(4))) float f32x4;

// ---------------- helpers ----------------
__device__ __forceinline__ unsigned short round1(float x) {
  // round-to-nearest-even bf16
  unsigned u = __builtin_bit_cast(unsigned, x);
  return (unsigned short)((u + 0x7FFFu + ((u >> 16) & 1u)) >> 16);
}

__device__ __forceinline__ float bdec(unsigned short h) {
  return __builtin_bit_cast(float, (unsigned)h << 16);
}

__device__ __forceinline__ void gload16(unsigned short* lds, const unsigned short* g) {
  // async global->LDS, 16B/lane; LDS dest = wave-uniform base + lane*16
  __builtin_amdgcn_global_load_lds(
      (const __attribute__((address_space(1))) unsigned int*)g,
      (__attribute__((address_space(3))) unsigned int*)lds, 16, 0, 0);
}

__global__ void k_zero(uint4* p, int n16) {
  int i = blockIdx.x * 256 + threadIdx.x;
  if (i < n16) p[i] = make_uint4(0, 0, 0, 0);
}

// 16-entry sigmoid edge-weight table: 16 waves, one per bond value
__global__ void k_ewtbl(const float* __restrict__ bh, const float* __restrict__ w,
                        const float* __restrict__ b, float* __restrict__ tbl) {
  int v = threadIdx.x >> 6, t = threadIdx.x & 63;
  float p = bh[v * 64 + t] * w[t];
  for (int off = 32; off; off >>= 1) p += __shfl_down(p, off, 64);
  if (t == 0) tbl[v] = 1.0f / (1.0f + expf(-(p + b[0])));
}

// Deterministic duplicate resolution: last edge (max e) wins.
__global__ void k_pack_adj(const int* __restrict__ lei, const int* __restrict__ ea,
                           int* __restrict__ packed) {
  int idx = blockIdx.x * 256 + threadIdx.x;       // NEDGE
  int g = idx >> 11, e = idx & 2047;
  int s = lei[g * 4096 + e];
  int d = lei[g * 4096 + 2048 + e];
  int v = ((e + 1) << 4) | ea[g * 2048 + e];
  atomicMax(&packed[g * 65536 + s * 256 + d], v);
}

// unpack + eye folded; writes EVERY element (no pre-zero of adj needed)
__global__ void k_unpack_adj(const int* __restrict__ packed,
                             const float* __restrict__ tbl, float* __restrict__ adj) {
  int idx = blockIdx.x * 256 + threadIdx.x;       // 8388608
  int v = packed[idx];
  int r = (idx >> 8) & 255, c = idx & 255;
  adj[idx] = (v ? tbl[v & 15] : 0.0f) + (r == c ? 1.0f : 0.0f);
}

// per-graph colsum^-1/2 and rowsum^-1/2 (sums only; scaling fused into k_ascale)
__global__ __launch_bounds__(256)
void k_degsums(const float* __restrict__ adj, float* __restrict__ CSv,
               float* __restrict__ RCv) {
  int g = blockIdx.x, t = threadIdx.x;
  const float* Ag = adj + (size_t)g * 65536;
  float s0 = 0, s1 = 0, s2 = 0, s3 = 0;
  for (int i = 0; i < 256; i += 4) {              // colsum(t), coalesced
    s0 += Ag[(i + 0) * 256 + t]; s1 += Ag[(i + 1) * 256 + t];
    s2 += Ag[(i + 2) * 256 + t]; s3 += Ag[(i + 3) * 256 + t];
  }
  CSv[g * 256 + t] = rsqrtf((s0 + s1) + (s2 + s3));
  float4 r0 = make_float4(0, 0, 0, 0), r1 = r0, r2 = r0, r3 = r0;
  const float4* A4 = (const float4*)(Ag + t * 256);
  for (int j = 0; j < 64; j += 4) {               // rowsum(t)
    float4 v0 = A4[j], v1 = A4[j + 1], v2 = A4[j + 2], v3 = A4[j + 3];
    r0.x += v0.x + v0.y; r0.y += v0.z + v0.w;
    r1.x += v1.x + v1.y; r1.y += v1.z + v1.w;
    r2.x += v2.x + v2.y; r2.y += v2.z + v2.w;
    r3.x += v3.x + v3.y; r3.y += v3.z + v3.w;
  }
  RCv[g * 256 + t] = rsqrtf((r0.x + r0.y) + (r1.x + r1.y) + (r2.x + r2.y) + (r3.x + r3.y));
}

// Ahb[g][i][j] = bf16( cs[i] * adj[i][j] * rc[j] )
__global__ void k_ascale(const float* __restrict__ adj, const float* __restrict__ CSv,
                         const float* __restrict__ RCv, unsigned short* __restrict__ Ahb) {
  int flat = blockIdx.x * 256 + threadIdx.x;      // 2097152 quads
  int g = flat >> 14;
  int i = (flat >> 6) & 255, j4 = (flat & 63) * 4;
  size_t base = (size_t)g * 65536 + i * 256 + j4;
  float4 a = *(const float4*)&adj[base];
  float cs = CSv[g * 256 + i];
  float4 rc = *(const float4*)&RCv[g * 256 + j4];
  ushort4 o;
  o.x = round1(cs * a.x * rc.x); o.y = round1(cs * a.y * rc.y);
  o.z = round1(cs * a.z * rc.z); o.w = round1(cs * a.w * rc.w);
  *(ushort4*)&Ahb[base] = o;
}

// transposed bf16 fea gather: X0h[g][e][n] = bf16(atom_emb[aidx[g*256+n]][e])
__global__ void k_feaTb(const int* __restrict__ aidx, const float* __restrict__ aemb,
                        unsigned short* __restrict__ X0h) {
  int flat = blockIdx.x * 256 + threadIdx.x;      // 2097152 quads
  int base = flat * 4;
  int g = base >> 16, e = (base >> 8) & 255, n0 = base & 255;
  const int* ai = &aidx[g * 256 + n0];
  ushort4 o;
  o.x = round1(aemb[ai[0] * 256 + e]);
  o.y = round1(aemb[ai[1] * 256 + e]);
  o.z = round1(aemb[ai[2] * 256 + e]);
  o.w = round1(aemb[ai[3] * 256 + e]);
  *(ushort4*)&X0h[base] = o;
}

// fused Y-sum + transpose: H0b[z][n][k] = bf16(0.25*(X0+X1+X2+X3)[z][k][n])
__global__ __launch_bounds__(256)
void k_sumT(const unsigned short* __restrict__ X0, const unsigned short* __restrict__ X1,
            const unsigned short* __restrict__ X2, const unsigned short* __restrict__ X3,
            unsigned short* __restrict__ dst) {
  __shared__ float tl[64][65];
  size_t zo = (size_t)blockIdx.z * 65536;
  int n0 = blockIdx.x * 64, k0 = blockIdx.y * 64;
  int t = threadIdx.x;
  int c = (t & 15) * 4, r = t >> 4;
#pragma unroll
  for (int p = 0; p < 4; p++) {
    int rr = r + p * 16;
    size_t off = zo + (size_t)(k0 + rr) * 256 + n0 + c;
    ushort4 a = *(const ushort4*)&X0[off];
    ushort4 b = *(const ushort4*)&X1[off];
    ushort4 cc = *(const ushort4*)&X2[off];
    ushort4 d = *(const ushort4*)&X3[off];
    tl[rr][c + 0] = bdec(a.x) + bdec(b.x) + bdec(cc.x) + bdec(d.x);
    tl[rr][c + 1] = bdec(a.y) + bdec(b.y) + bdec(cc.y) + bdec(d.y);
    tl[rr][c + 2] = bdec(a.z) + bdec(b.z) + bdec(cc.z) + bdec(d.z);
    tl[rr][c + 3] = bdec(a.w) + bdec(b.w) + bdec(cc.w) + bdec(d.w);
  }
  __syncthreads();
#pragma unroll
  for (int p = 0; p < 4; p++) {
    int rr = r + p * 16;
    ushort4 o;
    o.x = round1(tl[c][rr] * 0.25f);     o.y = round1(tl[c + 1][rr] * 0.25f);
    o.z = round1(tl[c + 2][rr] * 0.25f); o.w = round1(tl[c + 3][rr] * 0.25f);
    *(ushort4*)&dst[zo + (size_t)(n0 + rr) * 256 + k0 + c] = o;
  }
}

// weight transpose + bf16 round: dh[z][N][K] = bf16(src[z][K][N])
__global__ __launch_bounds__(256)
void k_wtb(const float* __restrict__ src, unsigned short* __restrict__ dh,
           int K, int N, long ss, long sd) {
  __shared__ float tl[64][65];
  src += (size_t)blockIdx.z * ss;
  dh += (size_t)blockIdx.z * sd;
  int n0 = blockIdx.x * 64, k0 = blockIdx.y * 64;
  int t = threadIdx.x;
  int c = (t & 15) * 4, r = t >> 4;
#pragma unroll
  for (int p = 0; p < 4; p++) {
    int rr = r + p * 16;
    float4 v = *(const float4*)&src[(size_t)(k0 + rr) * N + n0 + c];
    tl[rr][c] = v.x; tl[rr][c + 1] = v.y; tl[rr][c + 2] = v.z; tl[rr][c + 3] = v.w;
  }
  __syncthreads();
#pragma unroll
  for (int p = 0; p < 4; p++) {
    int rr = r + p * 16;
    ushort4 hh;
    hh.x = round1(tl[c][rr]);     hh.y = round1(tl[c + 1][rr]);
    hh.z = round1(tl[c + 2][rr]); hh.w = round1(tl[c + 3][rr]);
    *(ushort4*)&dh[(size_t)(n0 + rr) * K + k0 + c] = hh;
  }
}

// ---- bf16 GEMM (batched): C[z] = A[z] @ B[z]^T + bias; A[M][K], B[N][K] bf16.
// 32KB LDS, global_load_lds staging. Optional fused column sum/sumsq.
// Output: fp32 Cf and/or bf16 Ch.
__global__ __launch_bounds__(256, 4)
void k_bgemm(const unsigned short* __restrict__ A_g, const unsigned short* __restrict__ B_g,
             const float* __restrict__ bias, float* __restrict__ Cf,
             unsigned short* __restrict__ Ch,
             float* __restrict__ Ssum, float* __restrict__ Ssq, int K, int N,
             long zA, long zB, long zC) {
  __shared__ alignas(16) unsigned short As[128 * 64];
  __shared__ alignas(16) unsigned short Bs[128 * 64];
  int z = blockIdx.z;
  A_g += (size_t)z * zA; B_g += (size_t)z * zB;
  if (Cf) Cf += (size_t)z * zC;
  if (Ch) Ch += (size_t)z * zC;
  int rowbase = blockIdx.y * 128, colbase = blockIdx.x * 128;
  int t = threadIdx.x, l = t & 63, wid = t >> 6;
  int wr = wid >> 1, wc = wid & 1;
  int r8 = l >> 3, cb = (l & 7) * 8;               // staging lane -> (row, col)
  f32x4 acc[4][4];
#pragma unroll
  for (int i = 0; i < 4; i++)
#pragma unroll
    for (int j = 0; j < 4; j++) acc[i][j] = (f32x4){0, 0, 0, 0};

  for (int k0 = 0; k0 < K; k0 += 64) {
    __syncthreads();                               // prior readers done
#pragma unroll
    for (int i = 0; i < 4; i++) {
      int chunk = wid * 4 + i;                     // 0..15 -> 8 rows each
      int row = chunk * 8 + r8;
      gload16(As + chunk * 512, A_g + (size_t)(rowbase + row) * K + k0 + cb);
      gload16(Bs + chunk * 512, B_g + (size_t)(colbase + row) * K + k0 + cb);
    }
    __syncthreads();                               // vmcnt(0) drain + barrier
#pragma unroll
    for (int ks = 0; ks < 2; ks++) {
      bf16x8 ah[4], bh[4];
#pragma unroll
      for (int fm = 0; fm < 4; fm++) {
        int r = wr * 64 + fm * 16 + (l & 15);
        ah[fm] = *(const bf16x8*)&As[r * 64 + ks * 32 + (l >> 4) * 8];
      }
#pragma unroll
      for (int fn = 0; fn < 4; fn++) {
        int c = wc * 64 + fn * 16 + (l & 15);
        bh[fn] = *(const bf16x8*)&Bs[c * 64 + ks * 32 + (l >> 4) * 8];
      }
#pragma unroll
      for (int fm = 0; fm < 4; fm++)
#pragma unroll
        for (int fn = 0; fn < 4; fn++)
          acc[fm][fn] = __builtin_amdgcn_mfma_f32_16x16x32_bf16(ah[fm], bh[fn], acc[fm][fn], 0, 0, 0);
    }
  }
  __syncthreads();
  float bi[4], scoll[4] = {0, 0, 0, 0}, qcoll[4] = {0, 0, 0, 0};
#pragma unroll
  for (int fn = 0; fn < 4; fn++)
    bi[fn] = bias ? bias[colbase + wc * 64 + fn * 16 + (l & 15)] : 0.0f;
#pragma unroll
  for (int fm = 0; fm < 4; fm++)
#pragma unroll
    for (int r4 = 0; r4 < 4; r4++) {
      int row = rowbase + wr * 64 + fm * 16 + (l >> 4) * 4 + r4;
#pragma unroll
      for (int fn = 0; fn < 4; fn++) {
        int col = colbase + wc * 64 + fn * 16 + (l & 15);
        float v = acc[fm][fn][r4] + bi[fn];
        size_t idx = (size_t)row * N + col;
        if (Cf) Cf[idx] = v;
        if (Ch) Ch[idx] = round1(v);
        scoll[fn] += v; qcoll[fn] += v * v;
      }
    }
  if (Ssum) {
    float* scr = (float*)As;                       // 256 floats scratch
    scr[t] = 0.0f;
    __syncthreads();
#pragma unroll
    for (int fn = 0; fn < 4; fn++) {
      int cl_ = wc * 64 + fn * 16 + (l & 15);
      atomicAdd(&scr[cl_ * 2], scoll[fn]);
      atomicAdd(&scr[cl_ * 2 + 1], qcoll[fn]);
    }
    __syncthreads();
    if (t < 128) {
      atomicAdd(&Ssum[colbase + t], scr[t * 2]);
      atomicAdd(&Ssq[colbase + t], scr[t * 2 + 1]);
    }
  }
}

// in-place BN(+relu) on bf16 T1; BN1 finalize fused (reads raw stats)
__global__ void k_bnsplit(unsigned short* __restrict__ Th,
                          const float* __restrict__ Ssum, const float* __restrict__ Ssq,
                          const float* __restrict__ g, const float* __restrict__ b) {
  size_t i = (size_t)blockIdx.x * 256 + threadIdx.x;  // 4.19M threads x4 elems
  int c4 = ((int)i & 127) * 4;
  ushort4 h4 = *(ushort4*)&Th[i * 4];
  float4 ss = *(const float4*)&Ssum[c4], qq = *(const float4*)&Ssq[c4];
  float4 gg = *(const float4*)&g[c4],    bb = *(const float4*)&b[c4];
  const float invN = 1.0f / 32768.0f;
  float x, mu, var, sc, sh;
#define BNS(cmp) \
  mu = ss.cmp * invN; var = qq.cmp * invN - mu * mu; \
  sc = rsqrtf(var + 1e-5f) * gg.cmp; sh = bb.cmp - mu * sc; \
  x = bdec(h4.cmp); x = fmaf(x, sc, sh); x = x > 0 ? x : 0; \
  h4.cmp = round1(x);
  BNS(x) BNS(y) BNS(z) BNS(w)
#undef BNS
  *(ushort4*)&Th[i * 4] = h4;
}

// ---- CSR build (edge structure is layer-invariant; built once) ----
__global__ void k_count(const int* __restrict__ lei, int* __restrict__ counts) {
  int idx = blockIdx.x * 256 + threadIdx.x;
  int g = idx >> 11, e = idx & 2047;
  int d = lei[g * 4096 + 2048 + e];
  atomicAdd(&counts[g * 256 + d], 1);
}

__global__ void k_scan(const int* __restrict__ counts, int* __restrict__ rowptr,
                       int* __restrict__ pos) {
  int g = blockIdx.x, t = threadIdx.x;
  __shared__ int sc[256];
  int own = counts[g * 256 + t];
  sc[t] = own;
  __syncthreads();
  for (int off = 1; off < 256; off <<= 1) {
    int v = 0;
    if (t >= off) v = sc[t - off];
    __syncthreads();
    sc[t] += v;
    __syncthreads();
  }
  int val = g * 2048 + sc[t] - own; // exclusive
  rowptr[g * 256 + t] = val;
  pos[g * 256 + t] = val;
  if (g == B_G - 1 && t == 255) rowptr[B_G * 256] = B_G * 2048;
}

__global__ void k_fill(const int* __restrict__ lei, const int* __restrict__ ea,
                       int* __restrict__ pos, int* __restrict__ csr) {
  int idx = blockIdx.x * 256 + threadIdx.x;
  int g = idx >> 11, e = idx & 2047;
  int s = lei[g * 4096 + e];
  int d = lei[g * 4096 + 2048 + e];
  int eav = ea[g * 2048 + e];
  int slot = atomicAdd(&pos[g * 256 + d], 1);
  csr[slot] = s | (eav << 16);
}

// z = (1+eps)*(h+vn) + sum_{e->this} relu(h[src]+vn+eemb[ea]); H bf16, out bf16
// XCD-swizzled (bijective): graph's 64 blocks land on one XCD -> gather L2-hits
__global__ __launch_bounds__(256)
void k_agg(const unsigned short* __restrict__ H,
           const float* __restrict__ hsc, const float* __restrict__ hsh,
           const float* __restrict__ vn, int vns,
           const float* __restrict__ eemb,
           const int* __restrict__ rowptr, const int* __restrict__ csr,
           const float* __restrict__ geps, int l,
           unsigned short* __restrict__ Zh) {
  __shared__ float ee[16 * 256];
  for (int i = threadIdx.x; i < 4096; i += 256) ee[i] = eemb[i];
  __syncthreads();
  int lane = threadIdx.x & 63, w = threadIdx.x >> 6;
  int bid = (blockIdx.x & 7) * 1024 + (blockIdx.x >> 3);  // XCD swizzle, bijective
  int m = bid * 4 + w;
  int g = m >> 8;
  int d = lane * 4;
  float eps1 = 1.0f + geps[l];
  float4 sc4 = make_float4(0, 0, 0, 0), sh4 = make_float4(0, 0, 0, 0);
  if (hsc) { sc4 = *(const float4*)&hsc[d]; sh4 = *(const float4*)&hsh[d]; }
  float4 vn4 = *(const float4*)&vn[(size_t)g * vns + d];
  int rp = rowptr[m], rp1 = rowptr[m + 1];
  float4 acc = make_float4(0, 0, 0, 0);
  int gbase = g << 8;
  for (int j = rp; j < rp1; j++) {
    int cw = csr[j];
    int src = cw & 0xFFFF, eav = cw >> 16;
    ushort4 hr = *(const ushort4*)&H[(size_t)(gbase + src) * 256 + d];
    float4 h4 = make_float4(bdec(hr.x), bdec(hr.y), bdec(hr.z), bdec(hr.w));
    if (hsc) {
      h4.x = fmaf(h4.x, sc4.x, sh4.x); h4.y = fmaf(h4.y, sc4.y, sh4.y);
      h4.z = fmaf(h4.z, sc4.z, sh4.z); h4.w = fmaf(h4.w, sc4.w, sh4.w);
      h4.x = h4.x > 0 ? h4.x : 0; h4.y = h4.y > 0 ? h4.y : 0;
      h4.z = h4.z > 0 ? h4.z : 0; h4.w = h4.w > 0 ? h4.w : 0;
    }
    const float4 e4 = *(const float4*)&ee[eav * 256 + d];
    float mx = h4.x + vn4.x + e4.x; float my = h4.y + vn4.y + e4.y;
    float mz = h4.z + vn4.z + e4.z; float mw = h4.w + vn4.w + e4.w;
    acc.x += mx > 0 ? mx : 0; acc.y += my > 0 ? my : 0;
    acc.z += mz > 0 ? mz : 0; acc.w += mw > 0 ? mw : 0;
  }
  ushort4 hsr = *(const ushort4*)&H[(size_t)m * 256 + d];
  float4 hs = make_float4(bdec(hsr.x), bdec(hsr.y), bdec(hsr.z), bdec(hsr.w));
  if (hsc) {
    hs.x = fmaf(hs.x, sc4.x, sh4.x); hs.y = fmaf(hs.y, sc4.y, sh4.y);
    hs.z = fmaf(hs.z, sc4.z, sh4.z); hs.w = fmaf(hs.w, sc4.w, sh4.w);
    hs.x = hs.x > 0 ? hs.x : 0; hs.y = hs.y > 0 ? hs.y : 0;
    hs.z = hs.z > 0 ? hs.z : 0; hs.w = hs.w > 0 ? hs.w : 0;
  }
  float4 z4;
  z4.x = eps1 * (hs.x + vn4.x) + acc.x;
  z4.y = eps1 * (hs.y + vn4.y) + acc.y;
  z4.z = eps1 * (hs.z + vn4.z) + acc.z;
  z4.w = eps1 * (hs.w + vn4.w) + acc.w;
  ushort4 hh;
  hh.x = round1(z4.x); hh.y = round1(z4.y);
  hh.z = round1(z4.z); hh.w = round1(z4.w);
  *(ushort4*)&Zh[(size_t)m * 256 + d] = hh;
}

// contention-free partial colsums of transformed h (bf16): VNP[p][g][256]
__global__ __launch_bounds__(256)
void k_vnsum(const unsigned short* __restrict__ H,
             const float* __restrict__ hsc, const float* __restrict__ hsh,
             float* __restrict__ VNP) {
  int g = blockIdx.x >> 1, p = blockIdx.x & 1, t = threadIdx.x;
  float sc = 0, sh = 0;
  if (hsc) { sc = hsc[t]; sh = hsh[t]; }
  int base = g * 256 + p * 128;
  float s0 = 0, s1 = 0, s2 = 0, s3 = 0;           // 4-deep ILP
  for (int i = 0; i < 128; i += 4) {
    float v0 = bdec(H[(size_t)(base + i + 0) * 256 + t]);
    float v1 = bdec(H[(size_t)(base + i + 1) * 256 + t]);
    float v2 = bdec(H[(size_t)(base + i + 2) * 256 + t]);
    float v3 = bdec(H[(size_t)(base + i + 3) * 256 + t]);
    if (hsc) {
      v0 = fmaf(v0, sc, sh); v0 = v0 > 0 ? v0 : 0;
      v1 = fmaf(v1, sc, sh); v1 = v1 > 0 ? v1 : 0;
      v2 = fmaf(v2, sc, sh); v2 = v2 > 0 ? v2 : 0;
      v3 = fmaf(v3, sc, sh); v3 = v3 > 0 ? v3 : 0;
    }
    s0 += v0; s1 += v1; s2 += v2; s3 += v3;
  }
  VNP[(size_t)(p * 128 + g) * 256 + t] = (s0 + s1) + (s2 + s3);
}

// vn_out = relu(relu(vt@W1+B1)@W2+B2), vt = VNP[0][g]+VNP[1][g] + 257*vn
__global__ __launch_bounds__(256)
void k_vn(const float* __restrict__ VNP,
          const float* __restrict__ vn_in, int vns,
          const float* __restrict__ W1, const float* __restrict__ B1,
          const float* __restrict__ W2, const float* __restrict__ B2,
          float* __restrict__ vn_out) {
  int g = blockIdx.x, t = threadIdx.x;
  __shared__ float vt[256];
  __shared__ float u[512];
  vt[t] = VNP[(size_t)g * 256 + t] + VNP[(size_t)(128 + g) * 256 + t]
        + 257.0f * vn_in[(size_t)g * vns + t];
  __syncthreads();
  for (int o = t; o < 512; o += 256) {
    float a = B1[o];
    for (int k = 0; k < 256; k++) a = fmaf(vt[k], W1[k * 512 + o], a);
    u[o] = a > 0 ? a : 0;
  }
  __syncthreads();
  float a = B2[t];
  for (int k = 0; k < 512; k++) a = fmaf(u[k], W2[k * 256 + t], a);
  vn_out[g * 256 + t] = a > 0 ? a : 0;
}

__global__ void k_bnfin(const float* __restrict__ Ssum, const float* __restrict__ Ssq,
                        const float* __restrict__ g, const float* __restrict__ b,
                        float* __restrict__ scale, float* __restrict__ shift,
                        int NC, float invN) {
  int c = blockIdx.x * 256 + threadIdx.x;
  if (c >= NC) return;
  float mu = Ssum[c] * invN;
  float var = Ssq[c] * invN - mu * mu;
  float rs = rsqrtf(var + 1e-5f);
  float s = rs * g[c];
  scale[c] = s;
  shift[c] = b[c] - mu * s;
}

// out = t2*sc[c]+sh[c] (final BN, JK='last', no relu); T2 fp32 (last layer)
__global__ void k_final(const float* __restrict__ T2, const float* __restrict__ sc,
                        const float* __restrict__ sh, float* __restrict__ out) {
  int i = blockIdx.x * 256 + threadIdx.x; // 2097152 float4s
  int c4 = (i & 63) * 4;
  float4 v = *(const float4*)&T2[(size_t)i * 4];
  float4 s4 = *(const float4*)&sc[c4];
  float4 h4 = *(const float4*)&sh[c4];
  v.x = fmaf(v.x, s4.x, h4.x); v.y = fmaf(v.y, s4.y, h4.y);
  v.z = fmaf(v.z, s4.z, h4.z); v.w = fmaf(v.w, s4.w, h4.w);
  *(float4*)&out[(size_t)i * 4] = v;
}

extern "C" void kernel_launch(void* const* d_in, const int* in_sizes, int n_in,
                              void* d_out, int out_size, void* d_ws, size_t ws_size,
                              hipStream_t stream) {
  (void)in_sizes; (void)n_in; (void)out_size; (void)ws_size;
  const int*   atom_idx = (const int*)d_in[0];
  const int*   lei      = (const int*)d_in[1];
  const int*   eattr    = (const int*)d_in[2];
  const float* atom_emb = (const float*)d_in[4];
  const float* bemb_h   = (const float*)d_in[5];
  const float* elw      = (const float*)d_in[6];
  const float* elb      = (const float*)d_in[7];
  const float* bemb_l   = (const float*)d_in[8];
  const float* geps     = (const float*)d_in[9];
  const float* mw1      = (const float*)d_in[10];
  const float* mb1      = (const float*)d_in[11];
  const float* mbng     = (const float*)d_in[12];
  const float* mbnb     = (const float*)d_in[13];
  const float* mw2      = (const float*)d_in[14];
  const float* mb2      = (const float*)d_in[15];
  const float* obng     = (const float*)d_in[16];
  const float* obnb     = (const float*)d_in[17];
  const float* vne      = (const float*)d_in[18];
  const float* vw1      = (const float*)d_in[19];
  const float* vb1      = (const float*)d_in[20];
  const float* vw2      = (const float*)d_in[21];
  const float* vb2      = (const float*)d_in[22];
  float* out = (float*)d_out;

  // ws layout (33.55MB units):
  // U0: adj fp32 -> later T2b bf16 (lo half, layers 0..3) -> T2f fp32 (layer 4)
  // U1: X0h|X1h bf16 -> later T1h bf16 (full unit)
  // U2: X2h|X3h bf16
  // U3: PACKED int -> later H0b bf16 (lo half)
  // U4: Zh bf16 | Ahb bf16
  float* W   = (float*)d_ws;
  float* A_  = W;
  float* U1  = W + (size_t)FBUF;
  float* U2  = W + (size_t)2 * FBUF;
  float* U3  = W + (size_t)3 * FBUF;
  float* Z_  = W + (size_t)4 * FBUF;
  float* SM  = W + (size_t)5 * FBUF;
  float* EWT = SM;                   // 16
  float* S1S = SM + 256;             // 512
  float* S1Q = SM + 768;             // 512
  float* S2S = SM + 1280;            // 256
  float* S2Q = SM + 1536;            // 256  (S1S..S2Q contiguous 1536)
  float* SC2 = SM + 1792;            // 256
  float* SH2 = SM + 2048;            // 256
  float* VNA = SM + 2304;            // 32768
  float* VNB = SM + 35072;           // 32768
  float* CSv = SM + 67840;           // 32768
  float* RCv = SM + 100608;          // 32768
  int* ROWPTR = (int*)(SM + 133376); // 32772
  int* POS    = ROWPTR + 32772;      // 32768
  int* COUNTS = POS + 32768;         // 32768
  int* CSR    = COUNTS + 32768;      // 262144
  unsigned short* W1hT = (unsigned short*)(SM + 493952);  // 5*512*256 shorts
  unsigned short* W2hT = (unsigned short*)(SM + 821632);  // 5*256*512 shorts
  float* T2f = A_;                             // fp32, layer-4 output
  unsigned short* T2b = (unsigned short*)A_;   // bf16, layers 0..3 output
  unsigned short* H0b = (unsigned short*)U3;   // bf16 prop output
  int* PACKED = (int*)U3;
  unsigned short* X0h = (unsigned short*)U1;
  unsigned short* X1h = X0h + 8388608;
  unsigned short* X2h = (unsigned short*)U2;
  unsigned short* X3h = X2h + 8388608;
  unsigned short* T1h = (unsigned short*)U1;   // [32768][512] bf16 = full U1
  unsigned short* Zh  = (unsigned short*)Z_;   // [32768][256] bf16, U4 lo half
  unsigned short* Ahb = (unsigned short*)(Z_ + (size_t)FBUF / 2); // U4 hi half
  float* VNP  = (float*)POS;         // [2][128][256]; POS dead after CSR build

  // ---- stage 1: dense learned-adjacency propagation (bf16, transposed) ----
  k_zero<<<8192, 256, 0, stream>>>((uint4*)PACKED, 2097152);
  k_zero<<<32, 256, 0, stream>>>((uint4*)COUNTS, 8192);
  k_ewtbl<<<1, 1024, 0, stream>>>(bemb_h, elw, elb, EWT);
  k_pack_adj<<<NEDGE / 256, 256, 0, stream>>>(lei, eattr, PACKED);
  k_unpack_adj<<<32768, 256, 0, stream>>>(PACKED, EWT, A_);   // + eye
  k_degsums<<<B_G, 256, 0, stream>>>(A_, CSv, RCv);
  k_ascale<<<8192, 256, 0, stream>>>(A_, CSv, RCv, Ahb);
  // weight transpose + bf16 round (once)
  k_wtb<<<dim3(8, 4, 5), 256, 0, stream>>>(mw1, W1hT, 256, 512, 131072, 131072);
  k_wtb<<<dim3(4, 8, 5), 256, 0, stream>>>(mw2, W2hT, 512, 256, 131072, 131072);
  k_feaTb<<<8192, 256, 0, stream>>>(atom_idx, atom_emb, X0h);
  // order=3: Xt_{i+1} = Xt_i @ A^T (batched bf16 MFMA GEMM, no Y RMW)
  k_bgemm<<<dim3(2, 2, B_G), 256, 0, stream>>>(X0h, Ahb, nullptr, nullptr, X1h,
      nullptr, nullptr, 256, 256, 65536, 65536, 65536);
  k_bgemm<<<dim3(2, 2, B_G), 256, 0, stream>>>(X1h, Ahb, nullptr, nullptr, X2h,
      nullptr, nullptr, 256, 256, 65536, 65536, 65536);
  k_bgemm<<<dim3(2, 2, B_G), 256, 0, stream>>>(X2h, Ahb, nullptr, nullptr, X3h,
      nullptr, nullptr, 256, 256, 65536, 65536, 65536);
  // H0b[n][e] = bf16(0.25*(X0+X1+X2+X3)[e][n])  (PACKED dead; H0b = U3)
  k_sumT<<<dim3(4, 4, B_G), 256, 0, stream>>>(X0h, X1h, X2h, X3h, H0b);

  // ---- CSR (once; edges invariant across layers) ----
  k_count<<<NEDGE / 256, 256, 0, stream>>>(lei, COUNTS);
  k_scan<<<B_G, 256, 0, stream>>>(COUNTS, ROWPTR, POS);
  k_fill<<<NEDGE / 256, 256, 0, stream>>>(lei, eattr, POS, CSR);

  // ---- GIN + virtual-node stack ----
  const float* vn_cur = vne; int vns = 0;   // layer0 vn = vn_emb broadcast
  float* vn_next = VNA;
  for (int l = 0; l < NL; l++) {
    const unsigned short* hsrc = (l == 0) ? H0b : T2b;
    const float* hsc  = (l == 0) ? nullptr : SC2;
    const float* hsh  = (l == 0) ? nullptr : SH2;
    k_agg<<<NNODE / 4, 256, 0, stream>>>(hsrc, hsc, hsh, vn_cur, vns,
        bemb_l + (size_t)l * 16 * EMB, ROWPTR, CSR, geps, l, Zh);
    if (l < NL - 1) {
      k_vnsum<<<256, 256, 0, stream>>>(hsrc, hsc, hsh, VNP);
      k_vn<<<B_G, 256, 0, stream>>>(VNP, vn_cur, vns,
          vw1 + (size_t)l * EMB * 512, vb1 + (size_t)l * 512,
          vw2 + (size_t)l * 512 * EMB, vb2 + (size_t)l * EMB, vn_next);
    }
    k_zero<<<2, 256, 0, stream>>>((uint4*)S1S, 384);   // S1S,S1Q,S2S,S2Q
    k_bgemm<<<dim3(4, 256, 1), 256, 0, stream>>>(Zh,
        W1hT + (size_t)l * 131072, mb1 + (size_t)l * 512,
        nullptr, T1h, S1S, S1Q, 256, 512, 0, 0, 0);
    k_bnsplit<<<16384, 256, 0, stream>>>(T1h, S1S, S1Q,
        mbng + (size_t)l * 512, mbnb + (size_t)l * 512);
    // layers 0..3: bf16 T2b (consumed by next layer's gather);
    // layer 4: fp32 T2f (consumed by k_final -> fp32 output path)
    if (l < NL - 1)
      k_bgemm<<<dim3(2, 256, 1), 256, 0, stream>>>(T1h,
          W2hT + (size_t)l * 131072, mb2 + (size_t)l * 256,
          nullptr, T2b, S2S, S2Q, 512, 256, 0, 0, 0);
    else
      k_bgemm<<<dim3(2, 256, 1), 256, 0, stream>>>(T1h,
          W2hT + (size_t)l * 131072, mb2 + (size_t)l * 256,
          T2f, nullptr, S2S, S2Q, 512, 256, 0, 0, 0);
    k_bnfin<<<1, 256, 0, stream>>>(S2S, S2Q, obng + (size_t)l * EMB,
        obnb + (size_t)l * EMB, SC2, SH2, 256, 1.0f / NNODE);
    if (l < NL - 1) {
      vn_cur = vn_next; vns = EMB;
      vn_next = (vn_next == VNA) ? VNB : VNA;
    }
  }
  k_final<<<8192, 256, 0, stream>>>(T2f, SC2, SH2, out);
}